// Round 4
// baseline (587.389 us; speedup 1.0000x reference)
//
#include <hip/hip_runtime.h>
#include <hip/hip_bf16.h>
#include <cstdint>
#include <cstddef>

#define BATCH 2
#define SEQ 2048
#define DMODEL 1024
#define DIN 2048
#define NH 32
#define HEADDIM 64
#define DSTATE 64
#define DCONV 4
#define CONV_DIM (DIN + 2 * DSTATE)          // 2176
#define DPROJ (2 * DIN + 2 * DSTATE + NH)    // 4256
#define MLP_INNER 4096
#define TOKENS (BATCH * SEQ)                 // 4096
#define EPS 1e-5f
#define Q 64
#define NCHUNK (SEQ / Q)                     // 32
#define NCH (BATCH * NCHUNK * NH)            // 2048 chunk-heads
#define LSTR 72
#define NPAD_IN 4352                          // DPROJ padded to 34*128

typedef __attribute__((ext_vector_type(8))) short short8;
typedef __attribute__((ext_vector_type(8))) __bf16 bf16x8;
typedef __attribute__((ext_vector_type(4))) float f32x4;

__device__ inline short f2bf(float f) {
    unsigned u = __builtin_bit_cast(unsigned, f);
    u = (u + 0x7FFFu + ((u >> 16) & 1u)) >> 16;
    return (short)u;
}
__device__ inline float bf2f(short s) {
    unsigned u = ((unsigned)(unsigned short)s) << 16;
    return __builtin_bit_cast(float, u);
}
__device__ inline float silu_f(float x) { return x / (1.f + __expf(-x)); }

__device__ inline bf16x8 ld_frag(const short* p) {
    short8 s = *(const short8*)p;
    return __builtin_bit_cast(bf16x8, s);
}

__device__ inline void glds16(const short* g, short* l) {
    __builtin_amdgcn_global_load_lds(
        (const __attribute__((address_space(1))) void*)g,
        (__attribute__((address_space(3))) void*)l, 16, 0, 0);
}

// ---------------- bf16 GEMM, m97 structure, full-K ----------------
// MODE 0: f32 C = AB; 1: bf16 C = silu(AB+bias)
template <int MODE>
__global__ __launch_bounds__(256, 4) void gemm_bf16_kernel(
    const short* __restrict__ A, const short* __restrict__ BT,
    void* __restrict__ Cout, const float* __restrict__ bias,
    int M, int N, int K)
{
    const int tid  = threadIdx.x;
    const int wid  = tid >> 6;
    const int lane = tid & 63;
    const int lm   = lane & 15;
    const int lg   = lane >> 4;
    const int m0   = blockIdx.y * 128;
    const int n0   = blockIdx.x * 128;

    __shared__ __attribute__((aligned(16))) short Al[128 * 32];
    __shared__ __attribute__((aligned(16))) short Bl[128 * 32];

    f32x4 acc[4][4];
#pragma unroll
    for (int i = 0; i < 4; ++i)
#pragma unroll
        for (int j = 0; j < 4; ++j) acc[i][j] = {0.f, 0.f, 0.f, 0.f};

    const int wm = (wid >> 1) * 64;
    const int wn = (wid & 1) * 64;

    const int srow = lane >> 2;
    const int scol = (lane & 3) * 8;
    const short* Ag = A  + (size_t)(m0 + wid * 32 + srow) * K + scol;
    const short* Bg = BT + (size_t)(n0 + wid * 32 + srow) * K + scol;
    short* Ald = &Al[wid * 1024];
    short* Bld = &Bl[wid * 1024];

    for (int kt = 0; kt < K; kt += 32) {
        glds16(Ag + kt,           Ald);
        glds16(Ag + 16 * K + kt,  Ald + 512);
        glds16(Bg + kt,           Bld);
        glds16(Bg + 16 * K + kt,  Bld + 512);
        __syncthreads();

        bf16x8 af[4], bf[4];
#pragma unroll
        for (int i = 0; i < 4; ++i)
            af[i] = ld_frag(&Al[(wm + i * 16 + lm) * 32 + lg * 8]);
#pragma unroll
        for (int j = 0; j < 4; ++j)
            bf[j] = ld_frag(&Bl[(wn + j * 16 + lm) * 32 + lg * 8]);
#pragma unroll
        for (int i = 0; i < 4; ++i)
#pragma unroll
            for (int j = 0; j < 4; ++j)
                acc[i][j] = __builtin_amdgcn_mfma_f32_16x16x32_bf16(af[i], bf[j], acc[i][j], 0, 0, 0);
        __syncthreads();
    }

#pragma unroll
    for (int i = 0; i < 4; ++i) {
#pragma unroll
        for (int j = 0; j < 4; ++j) {
            int col = n0 + wn + j * 16 + lm;
            if (col >= N) continue;
            float bv = (MODE == 1) ? bias[col] : 0.f;
#pragma unroll
            for (int r = 0; r < 4; ++r) {
                int row = m0 + wm + i * 16 + lg * 4 + r;
                float v = acc[i][j][r];
                if (MODE == 1)
                    ((short*)Cout)[(size_t)row * N + col] = f2bf(silu_f(v + bv));
                else
                    ((float*)Cout)[(size_t)row * N + col] = v;
            }
        }
    }
}

// ---------------- split-K bf16 GEMM: C += A·B (slice), f32 atomics ----------------
// grid.z = K-slice; C must be pre-initialized (res/bias) by caller.
__global__ __launch_bounds__(256, 4) void gemm_splitk_kernel(
    const short* __restrict__ A, const short* __restrict__ BT,
    float* __restrict__ C, int M, int N, int K, int Ks)
{
    const int tid  = threadIdx.x;
    const int wid  = tid >> 6;
    const int lane = tid & 63;
    const int lm   = lane & 15;
    const int lg   = lane >> 4;
    const int m0   = blockIdx.y * 128;
    const int n0   = blockIdx.x * 128;
    const int kbeg = blockIdx.z * Ks;
    const int kend = kbeg + Ks;

    __shared__ __attribute__((aligned(16))) short Al[128 * 32];
    __shared__ __attribute__((aligned(16))) short Bl[128 * 32];

    f32x4 acc[4][4];
#pragma unroll
    for (int i = 0; i < 4; ++i)
#pragma unroll
        for (int j = 0; j < 4; ++j) acc[i][j] = {0.f, 0.f, 0.f, 0.f};

    const int wm = (wid >> 1) * 64;
    const int wn = (wid & 1) * 64;

    const int srow = lane >> 2;
    const int scol = (lane & 3) * 8;
    const short* Ag = A  + (size_t)(m0 + wid * 32 + srow) * K + scol;
    const short* Bg = BT + (size_t)(n0 + wid * 32 + srow) * K + scol;
    short* Ald = &Al[wid * 1024];
    short* Bld = &Bl[wid * 1024];

    for (int kt = kbeg; kt < kend; kt += 32) {
        glds16(Ag + kt,           Ald);
        glds16(Ag + 16 * K + kt,  Ald + 512);
        glds16(Bg + kt,           Bld);
        glds16(Bg + 16 * K + kt,  Bld + 512);
        __syncthreads();

        bf16x8 af[4], bf[4];
#pragma unroll
        for (int i = 0; i < 4; ++i)
            af[i] = ld_frag(&Al[(wm + i * 16 + lm) * 32 + lg * 8]);
#pragma unroll
        for (int j = 0; j < 4; ++j)
            bf[j] = ld_frag(&Bl[(wn + j * 16 + lm) * 32 + lg * 8]);
#pragma unroll
        for (int i = 0; i < 4; ++i)
#pragma unroll
            for (int j = 0; j < 4; ++j)
                acc[i][j] = __builtin_amdgcn_mfma_f32_16x16x32_bf16(af[i], bf[j], acc[i][j], 0, 0, 0);
        __syncthreads();
    }

#pragma unroll
    for (int i = 0; i < 4; ++i) {
#pragma unroll
        for (int j = 0; j < 4; ++j) {
            int col = n0 + wn + j * 16 + lm;
#pragma unroll
            for (int r = 0; r < 4; ++r) {
                int row = m0 + wm + i * 16 + lg * 4 + r;
                unsafeAtomicAdd(&C[(size_t)row * N + col], acc[i][j][r]);
            }
        }
    }
}

// ---------------- out = h + bias (init for MLP2 split-K) ----------------
__global__ __launch_bounds__(256) void initout_kernel(
    const float* __restrict__ h, const float* __restrict__ b, float* __restrict__ o)
{
    int i = blockIdx.x * 256 + threadIdx.x;          // element/4 index
    f32x4 v = *(const f32x4*)(h + (size_t)i * 4);
    int col = (i * 4) & (DMODEL - 1);
    f32x4 bb = *(const f32x4*)(b + col);
    v.x += bb.x; v.y += bb.y; v.z += bb.z; v.w += bb.w;
    *(f32x4*)(o + (size_t)i * 4) = v;
}

// ---------------- f32 -> bf16 convert ----------------
__global__ __launch_bounds__(256) void cvt_kernel(
    const float* __restrict__ src, short* __restrict__ dst, int n4)
{
    int i = (blockIdx.x * 256 + threadIdx.x);
    if (i >= n4) return;
    f32x4 v = *(const f32x4*)(src + (size_t)i * 4);
    short4 o;
    o.x = f2bf(v.x); o.y = f2bf(v.y); o.z = f2bf(v.z); o.w = f2bf(v.w);
    *(short4*)(dst + (size_t)i * 4) = o;
}

// ---------------- W [K][N] f32 -> WT [Npad][K] bf16 ----------------
__global__ __launch_bounds__(256) void transpose_kernel(
    const float* __restrict__ src, short* __restrict__ dst, int K, int N)
{
    __shared__ float t[32][33];
    int bx = blockIdx.x, by = blockIdx.y;
    int col = threadIdx.x & 31, row8 = threadIdx.x >> 5;
    int gn = bx * 32 + col;
#pragma unroll
    for (int r = 0; r < 4; ++r) {
        int gk = by * 32 + row8 + r * 8;
        t[row8 + r * 8][col] = (gn < N) ? src[(size_t)gk * N + gn] : 0.f;
    }
    __syncthreads();
#pragma unroll
    for (int r = 0; r < 4; ++r) {
        int n = bx * 32 + row8 + r * 8;
        dst[(size_t)n * K + by * 32 + col] = f2bf(t[col][row8 + r * 8]);
    }
}

// ---------------- depthwise causal conv (k=4) + bias + silu ----------------
__global__ __launch_bounds__(256) void conv_kernel(
    const float* __restrict__ zx, const float* __restrict__ cw,
    const float* __restrict__ cb, float* __restrict__ xBCc)
{
    int c4 = blockIdx.y * 256 + threadIdx.x;
    if (c4 >= CONV_DIM / 4) return;
    int m = blockIdx.x;
    int l = m & (SEQ - 1);
    int c = c4 * 4;
    const float* base = zx + (size_t)m * DPROJ + DIN + c;
    f32x4 acc = {0.f, 0.f, 0.f, 0.f};
#pragma unroll
    for (int j = 0; j < DCONV; ++j) {
        if (l - 3 + j < 0) continue;
        f32x4 xv = *(const f32x4*)(base + (ptrdiff_t)(j - 3) * DPROJ);
        acc.x += xv.x * cw[(c + 0) * DCONV + j];
        acc.y += xv.y * cw[(c + 1) * DCONV + j];
        acc.z += xv.z * cw[(c + 2) * DCONV + j];
        acc.w += xv.w * cw[(c + 3) * DCONV + j];
    }
    f32x4 o;
    o.x = silu_f(acc.x + cb[c + 0]);
    o.y = silu_f(acc.y + cb[c + 1]);
    o.z = silu_f(acc.z + cb[c + 2]);
    o.w = silu_f(acc.w + cb[c + 3]);
    *(f32x4*)(xBCc + (size_t)m * CONV_DIM + c) = o;
}

// ---------------- dt = softplus(dt_raw + bias); ldA = A * dt ----------------
__global__ __launch_bounds__(256) void dt_kernel(
    const float* __restrict__ zx, const float* __restrict__ dt_bias,
    const float* __restrict__ A_log, float* __restrict__ dtb, float* __restrict__ ldab)
{
    int idx = blockIdx.x * 256 + threadIdx.x;
    if (idx >= TOKENS * NH) return;
    int hh = idx & (NH - 1);
    int m  = idx >> 5;
    float v  = zx[(size_t)m * DPROJ + DIN + CONV_DIM + hh] + dt_bias[hh];
    float dt = (v > 20.f) ? v : log1pf(__expf(v));
    dtb[idx]  = dt;
    ldab[idx] = -__expf(A_log[hh]) * dt;
}

// ---------------- P1: intra-chunk SSD ----------------
__global__ __launch_bounds__(256) void chunk_kernel(
    const float* __restrict__ xBCc, const float* __restrict__ dtb,
    const float* __restrict__ ldab, float* __restrict__ ybuf,
    float* __restrict__ Sbuf, float* __restrict__ cumdecay)
{
    int bid = blockIdx.x;
    int h = bid & 31, c = (bid >> 5) & 31, b = bid >> 10;
    int m0 = b * SEQ + c * Q;
    int tid = threadIdx.x;
    int wid = tid >> 6, lane = tid & 63, lm = lane & 15, lg = lane >> 4;

    __shared__ __attribute__((aligned(16))) short Cc[64 * LSTR];
    __shared__ __attribute__((aligned(16))) short Bb[64 * LSTR];
    __shared__ __attribute__((aligned(16))) short BwT[64 * LSTR];
    __shared__ __attribute__((aligned(16))) short Xt[64 * LSTR];
    __shared__ __attribute__((aligned(16))) short Mm[64 * LSTR];
    __shared__ float Lc[64], dtv[64];

    if (tid < 64) {
        int s = tid;
        size_t ix = (size_t)(m0 + s) * NH + h;
        float ld = ldab[ix];
        float dt = dtb[ix];
        float v = ld;
#pragma unroll
        for (int off = 1; off < 64; off <<= 1) {
            float o = __shfl_up(v, off);
            if (s >= off) v += o;
        }
        Lc[s] = v;
        dtv[s] = dt;
        cumdecay[(size_t)bid * 64 + s] = __expf(v);
    }
    {
        int row = tid >> 2, c0 = (tid & 3) * 16;
        const float* pB = xBCc + (size_t)(m0 + row) * CONV_DIM + DIN;
#pragma unroll
        for (int u = 0; u < 4; ++u) {
            f32x4 vb = *(const f32x4*)(pB + c0 + 4 * u);
            f32x4 vc = *(const f32x4*)(pB + DSTATE + c0 + 4 * u);
            short4 sb, sc;
            sb.x = f2bf(vb.x); sb.y = f2bf(vb.y); sb.z = f2bf(vb.z); sb.w = f2bf(vb.w);
            sc.x = f2bf(vc.x); sc.y = f2bf(vc.y); sc.z = f2bf(vc.z); sc.w = f2bf(vc.w);
            *(short4*)&Bb[row * LSTR + c0 + 4 * u] = sb;
            *(short4*)&Cc[row * LSTR + c0 + 4 * u] = sc;
        }
    }
    __syncthreads();
    {
        int s = tid >> 2, c0 = (tid & 3) * 16;
        float w = dtv[s];
        float w2 = __expf(Lc[63] - Lc[s]);
        const float* pX = xBCc + (size_t)(m0 + s) * CONV_DIM + h * HEADDIM;
#pragma unroll
        for (int u = 0; u < 4; ++u) {
            f32x4 v = *(const f32x4*)(pX + c0 + 4 * u);
            Xt[(c0 + 4 * u + 0) * LSTR + s] = f2bf(v.x * w);
            Xt[(c0 + 4 * u + 1) * LSTR + s] = f2bf(v.y * w);
            Xt[(c0 + 4 * u + 2) * LSTR + s] = f2bf(v.z * w);
            Xt[(c0 + 4 * u + 3) * LSTR + s] = f2bf(v.w * w);
            short4 sb = *(short4*)&Bb[s * LSTR + c0 + 4 * u];
            BwT[(c0 + 4 * u + 0) * LSTR + s] = f2bf(bf2f(sb.x) * w2);
            BwT[(c0 + 4 * u + 1) * LSTR + s] = f2bf(bf2f(sb.y) * w2);
            BwT[(c0 + 4 * u + 2) * LSTR + s] = f2bf(bf2f(sb.z) * w2);
            BwT[(c0 + 4 * u + 3) * LSTR + s] = f2bf(bf2f(sb.w) * w2);
        }
    }
    __syncthreads();

    {
        bf16x8 af[2];
#pragma unroll
        for (int kk = 0; kk < 2; ++kk)
            af[kk] = ld_frag(&Cc[(wid * 16 + lm) * LSTR + kk * 32 + lg * 8]);
#pragma unroll
        for (int j = 0; j < 4; ++j) {
            f32x4 acc = {0.f, 0.f, 0.f, 0.f};
#pragma unroll
            for (int kk = 0; kk < 2; ++kk) {
                bf16x8 bf = ld_frag(&Bb[(j * 16 + lm) * LSTR + kk * 32 + lg * 8]);
                acc = __builtin_amdgcn_mfma_f32_16x16x32_bf16(af[kk], bf, acc, 0, 0, 0);
            }
            int s = j * 16 + lm;
            float Ls = Lc[s];
#pragma unroll
            for (int r = 0; r < 4; ++r) {
                int t = wid * 16 + lg * 4 + r;
                float val = (s <= t) ? acc[r] * __expf(Lc[t] - Ls) : 0.f;
                Mm[t * LSTR + s] = f2bf(val);
            }
        }
    }
    __syncthreads();

    {
        bf16x8 am[2], aw[2];
#pragma unroll
        for (int kk = 0; kk < 2; ++kk) {
            am[kk] = ld_frag(&Mm[(wid * 16 + lm) * LSTR + kk * 32 + lg * 8]);
            aw[kk] = ld_frag(&BwT[(wid * 16 + lm) * LSTR + kk * 32 + lg * 8]);
        }
#pragma unroll
        for (int j = 0; j < 4; ++j) {
            f32x4 a1 = {0.f, 0.f, 0.f, 0.f};
            f32x4 a2 = {0.f, 0.f, 0.f, 0.f};
#pragma unroll
            for (int kk = 0; kk < 2; ++kk) {
                bf16x8 bx = ld_frag(&Xt[(j * 16 + lm) * LSTR + kk * 32 + lg * 8]);
                a1 = __builtin_amdgcn_mfma_f32_16x16x32_bf16(am[kk], bx, a1, 0, 0, 0);
                a2 = __builtin_amdgcn_mfma_f32_16x16x32_bf16(aw[kk], bx, a2, 0, 0, 0);
            }
            int p = j * 16 + lm;
#pragma unroll
            for (int r = 0; r < 4; ++r) {
                int t = wid * 16 + lg * 4 + r;
                ybuf[(size_t)(m0 + t) * DIN + h * HEADDIM + p] = a1[r];
                Sbuf[(size_t)bid * 4096 + t * 64 + p] = a2[r];
            }
        }
    }
}

// ---------------- P2: inter-chunk state recurrence ----------------
__global__ __launch_bounds__(256) void state_kernel(
    float* __restrict__ SH, const float* __restrict__ cumdecay)
{
    int bh = blockIdx.x;
    int b = bh >> 5, h = bh & 31;
    int tid = threadIdx.x;
    f32x4 H[4];
#pragma unroll
    for (int u = 0; u < 4; ++u) H[u] = {0.f, 0.f, 0.f, 0.f};
    for (int c = 0; c < NCHUNK; ++c) {
        int cid = (b * NCHUNK + c) * NH + h;
        size_t base = (size_t)cid * 4096 + (size_t)tid * 16;
        float cd = cumdecay[(size_t)cid * 64 + 63];
        f32x4 s[4];
#pragma unroll
        for (int u = 0; u < 4; ++u) s[u] = *(const f32x4*)(SH + base + u * 4);
#pragma unroll
        for (int u = 0; u < 4; ++u) *(f32x4*)(SH + base + u * 4) = H[u];
#pragma unroll
        for (int u = 0; u < 4; ++u) {
            H[u].x = cd * H[u].x + s[u].x;
            H[u].y = cd * H[u].y + s[u].y;
            H[u].z = cd * H[u].z + s[u].z;
            H[u].w = cd * H[u].w + s[u].w;
        }
    }
}

// ---------------- P3: y += exp(Lc_t) * C_t @ H_in ----------------
__global__ __launch_bounds__(256) void inter_kernel(
    const float* __restrict__ xBCc, const float* __restrict__ Hin,
    const float* __restrict__ cumdecay, float* __restrict__ ybuf)
{
    int bid = blockIdx.x;
    int h = bid & 31, c = (bid >> 5) & 31, b = bid >> 10;
    int m0 = b * SEQ + c * Q;
    int tid = threadIdx.x;
    int wid = tid >> 6, lane = tid & 63, lm = lane & 15, lg = lane >> 4;

    __shared__ __attribute__((aligned(16))) short Cc[64 * LSTR];
    __shared__ __attribute__((aligned(16))) short HT[64 * LSTR];
    __shared__ float eLc[64];

    if (tid < 64) eLc[tid] = cumdecay[(size_t)bid * 64 + tid];
    {
        int row = tid >> 2, c0 = (tid & 3) * 16;
        const float* pC = xBCc + (size_t)(m0 + row) * CONV_DIM + DIN + DSTATE;
        const float* pH = Hin + (size_t)bid * 4096 + row * 64;
#pragma unroll
        for (int u = 0; u < 4; ++u) {
            f32x4 vc = *(const f32x4*)(pC + c0 + 4 * u);
            short4 sc;
            sc.x = f2bf(vc.x); sc.y = f2bf(vc.y); sc.z = f2bf(vc.z); sc.w = f2bf(vc.w);
            *(short4*)&Cc[row * LSTR + c0 + 4 * u] = sc;
            f32x4 vh = *(const f32x4*)(pH + c0 + 4 * u);
            HT[(c0 + 4 * u + 0) * LSTR + row] = f2bf(vh.x);
            HT[(c0 + 4 * u + 1) * LSTR + row] = f2bf(vh.y);
            HT[(c0 + 4 * u + 2) * LSTR + row] = f2bf(vh.z);
            HT[(c0 + 4 * u + 3) * LSTR + row] = f2bf(vh.w);
        }
    }
    __syncthreads();

    bf16x8 af[2];
#pragma unroll
    for (int kk = 0; kk < 2; ++kk)
        af[kk] = ld_frag(&Cc[(wid * 16 + lm) * LSTR + kk * 32 + lg * 8]);
#pragma unroll
    for (int j = 0; j < 4; ++j) {
        f32x4 acc = {0.f, 0.f, 0.f, 0.f};
#pragma unroll
        for (int kk = 0; kk < 2; ++kk) {
            bf16x8 bh_ = ld_frag(&HT[(j * 16 + lm) * LSTR + kk * 32 + lg * 8]);
            acc = __builtin_amdgcn_mfma_f32_16x16x32_bf16(af[kk], bh_, acc, 0, 0, 0);
        }
        int p = j * 16 + lm;
#pragma unroll
        for (int r = 0; r < 4; ++r) {
            int t = wid * 16 + lg * 4 + r;
            size_t ya = (size_t)(m0 + t) * DIN + h * HEADDIM + p;
            ybuf[ya] += eLc[t] * acc[r];
        }
    }
}

// ---------------- ybf = bf16(rmsnorm((y + D*x) * silu(z), norm_w)) ----------------
__global__ __launch_bounds__(256) void norm1_kernel(
    const float* __restrict__ zx, const float* __restrict__ xBCc,
    const float* __restrict__ Dp, const float* __restrict__ y,
    short* __restrict__ ybf, const float* __restrict__ w)
{
    int m = blockIdx.x;
    int t = threadIdx.x;
    const float* zr = zx + (size_t)m * DPROJ;
    const float* xr = xBCc + (size_t)m * CONV_DIM;
    const float* yr = y + (size_t)m * DIN;
    float vals[8];
    float ss = 0.f;
#pragma unroll
    for (int j = 0; j < 8; ++j) {
        int i = j * 256 + t;
        float v = (yr[i] + Dp[i >> 6] * xr[i]) * silu_f(zr[i]);
        vals[j] = v;
        ss += v * v;
    }
#pragma unroll
    for (int o = 32; o >= 1; o >>= 1) ss += __shfl_xor(ss, o);
    __shared__ float wsum[4];
    if ((t & 63) == 0) wsum[t >> 6] = ss;
    __syncthreads();
    float tot = wsum[0] + wsum[1] + wsum[2] + wsum[3];
    float scale = rsqrtf(tot / (float)DIN + EPS);
#pragma unroll
    for (int j = 0; j < 8; ++j) {
        int i = j * 256 + t;
        ybf[(size_t)m * DIN + i] = f2bf(vals[j] * scale * w[i]);
    }
}

// ---------------- hnbf = bf16(rmsnorm(h, rms_w)) ----------------
__global__ __launch_bounds__(256) void norm2_kernel(
    const float* __restrict__ hb, short* __restrict__ hnbf, const float* __restrict__ w)
{
    int m = blockIdx.x;
    int t = threadIdx.x;
    const float* hr = hb + (size_t)m * DMODEL;
    float vals[4];
    float ss = 0.f;
#pragma unroll
    for (int j = 0; j < 4; ++j) {
        int i = j * 256 + t;
        float v = hr[i];
        vals[j] = v;
        ss += v * v;
    }
#pragma unroll
    for (int o = 32; o >= 1; o >>= 1) ss += __shfl_xor(ss, o);
    __shared__ float wsum[4];
    if ((t & 63) == 0) wsum[t >> 6] = ss;
    __syncthreads();
    float tot = wsum[0] + wsum[1] + wsum[2] + wsum[3];
    float scale = rsqrtf(tot / (float)DMODEL + EPS);
#pragma unroll
    for (int j = 0; j < 4; ++j) {
        int i = j * 256 + t;
        hnbf[(size_t)m * DMODEL + i] = f2bf(vals[j] * scale * w[i]);
    }
}

extern "C" void kernel_launch(void* const* d_in, const int* in_sizes, int n_in,
                              void* d_out, int out_size, void* d_ws, size_t ws_size,
                              hipStream_t stream) {
    const float* x       = (const float*)d_in[0];
    const float* W_in    = (const float*)d_in[1];
    const float* conv_w  = (const float*)d_in[2];
    const float* conv_b  = (const float*)d_in[3];
    const float* dt_bias = (const float*)d_in[4];
    const float* A_log   = (const float*)d_in[5];
    const float* D_param = (const float*)d_in[6];
    const float* norm_w  = (const float*)d_in[7];
    const float* W_out   = (const float*)d_in[8];
    const float* rms_w   = (const float*)d_in[9];
    const float* mlp_w1  = (const float*)d_in[10];
    const float* mlp_b1  = (const float*)d_in[11];
    const float* mlp_w2  = (const float*)d_in[12];
    const float* mlp_b2  = (const float*)d_in[13];
    float* out = (float*)d_out;

    float* ws       = (float*)d_ws;
    float* zx       = ws;
    float* xBCc     = zx + (size_t)TOKENS * DPROJ;
    float* dtb      = xBCc + (size_t)TOKENS * CONV_DIM;
    float* ldab     = dtb + (size_t)TOKENS * NH;
    float* cumdecay = ldab + (size_t)TOKENS * NH;
    float* ybuf     = cumdecay + (size_t)TOKENS * NH;
    float* SH       = ybuf + (size_t)TOKENS * DIN;
    float* bfarea   = SH + (size_t)NCH * 4096;

    short* xbf   = (short*)ybuf;
    short* midbf = (short*)ybuf;
    float* hbuf  = SH;
    short* hnbf  = (short*)(SH + (size_t)TOKENS * DMODEL);

    short* ybf   = (short*)bfarea;
    short* WinT  = ybf + (size_t)TOKENS * DIN;
    short* WoutT = WinT + (size_t)NPAD_IN * DMODEL;
    short* w1T   = WoutT + (size_t)DMODEL * DIN;
    short* w2T   = w1T + (size_t)MLP_INNER * DMODEL;

    dim3 blk(256);

    // 0. conversions / weight transposes
    cvt_kernel<<<dim3(TOKENS * DMODEL / 4 / 256), blk, 0, stream>>>(x, xbf, TOKENS * DMODEL / 4);
    transpose_kernel<<<dim3(NPAD_IN / 32, DMODEL / 32), blk, 0, stream>>>(W_in, WinT, DMODEL, DPROJ);
    transpose_kernel<<<dim3(DMODEL / 32, DIN / 32), blk, 0, stream>>>(W_out, WoutT, DIN, DMODEL);
    transpose_kernel<<<dim3(MLP_INNER / 32, DMODEL / 32), blk, 0, stream>>>(mlp_w1, w1T, DMODEL, MLP_INNER);
    transpose_kernel<<<dim3(DMODEL / 32, MLP_INNER / 32), blk, 0, stream>>>(mlp_w2, w2T, MLP_INNER, DMODEL);

    // 1. zx = x @ W_in
    gemm_bf16_kernel<0><<<dim3(NPAD_IN / 128, TOKENS / 128), blk, 0, stream>>>(
        xbf, WinT, zx, nullptr, TOKENS, DPROJ, DMODEL);
    // 2. conv + bias + silu
    conv_kernel<<<dim3(TOKENS, (CONV_DIM / 4 + 255) / 256), blk, 0, stream>>>(
        zx, conv_w, conv_b, xBCc);
    // 3. dt / ldA
    dt_kernel<<<dim3(TOKENS * NH / 256), blk, 0, stream>>>(zx, dt_bias, A_log, dtb, ldab);
    // 4. SSD
    chunk_kernel<<<dim3(NCH), blk, 0, stream>>>(xBCc, dtb, ldab, ybuf, SH, cumdecay);
    state_kernel<<<dim3(BATCH * NH), blk, 0, stream>>>(SH, cumdecay);
    inter_kernel<<<dim3(NCH), blk, 0, stream>>>(xBCc, SH, cumdecay, ybuf);
    // 5. ybf = bf16(rmsnorm((y + D*x) * silu(z)))
    norm1_kernel<<<dim3(TOKENS), blk, 0, stream>>>(zx, xBCc, D_param, ybuf, ybf, norm_w);
    // 6. h = x + ybf @ W_out   (init hbuf = x, then split-K atomic accumulate)
    hipMemcpyAsync(hbuf, x, (size_t)TOKENS * DMODEL * sizeof(float),
                   hipMemcpyDeviceToDevice, stream);
    gemm_splitk_kernel<<<dim3(DMODEL / 128, TOKENS / 128, 4), blk, 0, stream>>>(
        ybf, WoutT, hbuf, TOKENS, DMODEL, DIN, DIN / 4);
    // 7. hnbf = bf16(rmsnorm(h))
    norm2_kernel<<<dim3(TOKENS), blk, 0, stream>>>(hbuf, hnbf, rms_w);
    // 8. midbf = bf16(silu(hnbf @ mlp_w1 + b1))
    gemm_bf16_kernel<1><<<dim3(MLP_INNER / 128, TOKENS / 128), blk, 0, stream>>>(
        hnbf, w1T, midbf, mlp_b1, TOKENS, MLP_INNER, DMODEL);
    // 9. out = h + b2 + midbf @ mlp_w2   (init out = h + b2, then split-K atomic)
    initout_kernel<<<dim3(TOKENS * DMODEL / 4 / 256), blk, 0, stream>>>(hbuf, mlp_b2, out);
    gemm_splitk_kernel<<<dim3(DMODEL / 128, TOKENS / 128, 4), blk, 0, stream>>>(
        midbf, w2T, out, TOKENS, DMODEL, MLP_INNER, MLP_INNER / 4);
}

// Round 5
// 525.622 us; speedup vs baseline: 1.1175x; 1.1175x over previous
//
#include <hip/hip_runtime.h>
#include <hip/hip_bf16.h>
#include <cstdint>
#include <cstddef>

#define BATCH 2
#define SEQ 2048
#define DMODEL 1024
#define DIN 2048
#define NH 32
#define HEADDIM 64
#define DSTATE 64
#define DCONV 4
#define CONV_DIM (DIN + 2 * DSTATE)          // 2176
#define DPROJ (2 * DIN + 2 * DSTATE + NH)    // 4256
#define MLP_INNER 4096
#define TOKENS (BATCH * SEQ)                 // 4096
#define EPS 1e-5f
#define Q 64
#define NCHUNK (SEQ / Q)                     // 32
#define NCH (BATCH * NCHUNK * NH)            // 2048 chunk-heads
#define LSTR 72
#define NPAD_IN 4352                          // DPROJ padded to 34*128

typedef __attribute__((ext_vector_type(8))) short short8;
typedef __attribute__((ext_vector_type(8))) __bf16 bf16x8;
typedef __attribute__((ext_vector_type(4))) float f32x4;

__device__ inline short f2bf(float f) {
    unsigned u = __builtin_bit_cast(unsigned, f);
    u = (u + 0x7FFFu + ((u >> 16) & 1u)) >> 16;
    return (short)u;
}
__device__ inline float bf2f(short s) {
    unsigned u = ((unsigned)(unsigned short)s) << 16;
    return __builtin_bit_cast(float, u);
}
__device__ inline float silu_f(float x) { return x / (1.f + __expf(-x)); }

__device__ inline bf16x8 ld_frag(const short* p) {
    short8 s = *(const short8*)p;
    return __builtin_bit_cast(bf16x8, s);
}

__device__ inline void glds16(const short* g, short* l) {
    __builtin_amdgcn_global_load_lds(
        (const __attribute__((address_space(1))) void*)g,
        (__attribute__((address_space(3))) void*)l, 16, 0, 0);
}

// ---------------- bf16 GEMM, m97 structure + LDS double-buffer + XCD swizzle ----
// A: [M][K] bf16 row-major. BT: [Npad][K] bf16. BK=32, tile 128x128.
// MODE 0: f32 C = AB; 1: bf16 C = silu(AB+bias); 2: f32 C = AB+bias+res; 3: f32 C = AB+res
template <int MODE>
__global__ __launch_bounds__(256, 4) void gemm_bf16_kernel(
    const short* __restrict__ A, const short* __restrict__ BT,
    void* __restrict__ Cout, const float* __restrict__ bias,
    const float* __restrict__ res, int M, int N, int K)
{
    const int tid  = threadIdx.x;
    const int wid  = tid >> 6;
    const int lane = tid & 63;
    const int lm   = lane & 15;
    const int lg   = lane >> 4;

    // XCD-aware swizzle: give each XCD a contiguous y-tile (A-row) range so
    // per-XCD L2 holds a small A slice; B re-reads hit L3.
    const int nb  = gridDim.x * gridDim.y;
    const int bid = blockIdx.y * gridDim.x + blockIdx.x;
    const int per = nb >> 3;
    const int nid = (bid & 7) * per + (bid >> 3);
    const int m0  = (nid / gridDim.x) * 128;
    const int n0  = (nid % gridDim.x) * 128;

    __shared__ __attribute__((aligned(16))) short Al0[128 * 32];
    __shared__ __attribute__((aligned(16))) short Al1[128 * 32];
    __shared__ __attribute__((aligned(16))) short Bl0[128 * 32];
    __shared__ __attribute__((aligned(16))) short Bl1[128 * 32];

    f32x4 acc[4][4];
#pragma unroll
    for (int i = 0; i < 4; ++i)
#pragma unroll
        for (int j = 0; j < 4; ++j) acc[i][j] = {0.f, 0.f, 0.f, 0.f};

    const int wm = (wid >> 1) * 64;
    const int wn = (wid & 1) * 64;

    const int srow = lane >> 2;
    const int scol = (lane & 3) * 8;
    const short* Ag = A  + (size_t)(m0 + wid * 32 + srow) * K + scol;
    const short* Bg = BT + (size_t)(n0 + wid * 32 + srow) * K + scol;

    const int niter = K >> 5;
    // prologue: stage tile 0 into buf0
    {
        short* al = Al0 + wid * 1024;
        short* bl = Bl0 + wid * 1024;
        glds16(Ag, al);           glds16(Ag + 16 * K, al + 512);
        glds16(Bg, bl);           glds16(Bg + 16 * K, bl + 512);
    }

    for (int i = 0; i < niter; ++i) {
        __syncthreads();   // drains staging loads of buf[i&1]; protects overwrite
        const short* Ac = (i & 1) ? Al1 : Al0;
        const short* Bc = (i & 1) ? Bl1 : Bl0;
        if (i + 1 < niter) {
            int kt = (i + 1) << 5;
            short* al = ((i & 1) ? Al0 : Al1) + wid * 1024;
            short* bl = ((i & 1) ? Bl0 : Bl1) + wid * 1024;
            glds16(Ag + kt, al);          glds16(Ag + 16 * K + kt, al + 512);
            glds16(Bg + kt, bl);          glds16(Bg + 16 * K + kt, bl + 512);
        }

        bf16x8 af[4], bf[4];
#pragma unroll
        for (int ii = 0; ii < 4; ++ii)
            af[ii] = ld_frag(&Ac[(wm + ii * 16 + lm) * 32 + lg * 8]);
#pragma unroll
        for (int j = 0; j < 4; ++j)
            bf[j] = ld_frag(&Bc[(wn + j * 16 + lm) * 32 + lg * 8]);
#pragma unroll
        for (int ii = 0; ii < 4; ++ii)
#pragma unroll
            for (int j = 0; j < 4; ++j)
                acc[ii][j] = __builtin_amdgcn_mfma_f32_16x16x32_bf16(af[ii], bf[j], acc[ii][j], 0, 0, 0);
    }

#pragma unroll
    for (int i = 0; i < 4; ++i) {
#pragma unroll
        for (int j = 0; j < 4; ++j) {
            int col = n0 + wn + j * 16 + lm;
            if (col >= N) continue;
            float bv = (MODE == 1 || MODE == 2) ? bias[col] : 0.f;
#pragma unroll
            for (int r = 0; r < 4; ++r) {
                int row = m0 + wm + i * 16 + lg * 4 + r;
                float v = acc[i][j][r];
                if (MODE == 1) {
                    ((short*)Cout)[(size_t)row * N + col] = f2bf(silu_f(v + bv));
                } else {
                    if (MODE == 2) v = v + bv + res[(size_t)row * N + col];
                    if (MODE == 3) v = v + res[(size_t)row * N + col];
                    ((float*)Cout)[(size_t)row * N + col] = v;
                }
            }
        }
    }
}

// ---------------- f32 -> bf16 convert ----------------
__global__ __launch_bounds__(256) void cvt_kernel(
    const float* __restrict__ src, short* __restrict__ dst, int n4)
{
    int i = (blockIdx.x * 256 + threadIdx.x);
    if (i >= n4) return;
    f32x4 v = *(const f32x4*)(src + (size_t)i * 4);
    short4 o;
    o.x = f2bf(v.x); o.y = f2bf(v.y); o.z = f2bf(v.z); o.w = f2bf(v.w);
    *(short4*)(dst + (size_t)i * 4) = o;
}

// ---------------- W [K][N] f32 -> WT [Npad][K] bf16 ----------------
__global__ __launch_bounds__(256) void transpose_kernel(
    const float* __restrict__ src, short* __restrict__ dst, int K, int N)
{
    __shared__ float t[32][33];
    int bx = blockIdx.x, by = blockIdx.y;
    int col = threadIdx.x & 31, row8 = threadIdx.x >> 5;
    int gn = bx * 32 + col;
#pragma unroll
    for (int r = 0; r < 4; ++r) {
        int gk = by * 32 + row8 + r * 8;
        t[row8 + r * 8][col] = (gn < N) ? src[(size_t)gk * N + gn] : 0.f;
    }
    __syncthreads();
#pragma unroll
    for (int r = 0; r < 4; ++r) {
        int n = bx * 32 + row8 + r * 8;
        dst[(size_t)n * K + by * 32 + col] = f2bf(t[col][row8 + r * 8]);
    }
}

// ---------------- depthwise causal conv (k=4) + bias + silu ----------------
__global__ __launch_bounds__(256) void conv_kernel(
    const float* __restrict__ zx, const float* __restrict__ cw,
    const float* __restrict__ cb, float* __restrict__ xBCc)
{
    int c4 = blockIdx.y * 256 + threadIdx.x;
    if (c4 >= CONV_DIM / 4) return;
    int m = blockIdx.x;
    int l = m & (SEQ - 1);
    int c = c4 * 4;
    const float* base = zx + (size_t)m * DPROJ + DIN + c;
    f32x4 acc = {0.f, 0.f, 0.f, 0.f};
#pragma unroll
    for (int j = 0; j < DCONV; ++j) {
        if (l - 3 + j < 0) continue;
        f32x4 xv = *(const f32x4*)(base + (ptrdiff_t)(j - 3) * DPROJ);
        acc.x += xv.x * cw[(c + 0) * DCONV + j];
        acc.y += xv.y * cw[(c + 1) * DCONV + j];
        acc.z += xv.z * cw[(c + 2) * DCONV + j];
        acc.w += xv.w * cw[(c + 3) * DCONV + j];
    }
    f32x4 o;
    o.x = silu_f(acc.x + cb[c + 0]);
    o.y = silu_f(acc.y + cb[c + 1]);
    o.z = silu_f(acc.z + cb[c + 2]);
    o.w = silu_f(acc.w + cb[c + 3]);
    *(f32x4*)(xBCc + (size_t)m * CONV_DIM + c) = o;
}

// ---------------- dt = softplus(dt_raw + bias); ldA = A * dt ----------------
__global__ __launch_bounds__(256) void dt_kernel(
    const float* __restrict__ zx, const float* __restrict__ dt_bias,
    const float* __restrict__ A_log, float* __restrict__ dtb, float* __restrict__ ldab)
{
    int idx = blockIdx.x * 256 + threadIdx.x;
    if (idx >= TOKENS * NH) return;
    int hh = idx & (NH - 1);
    int m  = idx >> 5;
    float v  = zx[(size_t)m * DPROJ + DIN + CONV_DIM + hh] + dt_bias[hh];
    float dt = (v > 20.f) ? v : log1pf(__expf(v));
    dtb[idx]  = dt;
    ldab[idx] = -__expf(A_log[hh]) * dt;
}

// ---------------- P1: intra-chunk SSD ----------------
__global__ __launch_bounds__(256) void chunk_kernel(
    const float* __restrict__ xBCc, const float* __restrict__ dtb,
    const float* __restrict__ ldab, float* __restrict__ ybuf,
    float* __restrict__ Sbuf, float* __restrict__ cumdecay)
{
    int bid = blockIdx.x;
    int h = bid & 31, c = (bid >> 5) & 31, b = bid >> 10;
    int m0 = b * SEQ + c * Q;
    int tid = threadIdx.x;
    int wid = tid >> 6, lane = tid & 63, lm = lane & 15, lg = lane >> 4;

    __shared__ __attribute__((aligned(16))) short Cc[64 * LSTR];
    __shared__ __attribute__((aligned(16))) short Bb[64 * LSTR];
    __shared__ __attribute__((aligned(16))) short BwT[64 * LSTR];
    __shared__ __attribute__((aligned(16))) short Xt[64 * LSTR];
    __shared__ __attribute__((aligned(16))) short Mm[64 * LSTR];
    __shared__ float Lc[64], dtv[64];

    if (tid < 64) {
        int s = tid;
        size_t ix = (size_t)(m0 + s) * NH + h;
        float ld = ldab[ix];
        float dt = dtb[ix];
        float v = ld;
#pragma unroll
        for (int off = 1; off < 64; off <<= 1) {
            float o = __shfl_up(v, off);
            if (s >= off) v += o;
        }
        Lc[s] = v;
        dtv[s] = dt;
        cumdecay[(size_t)bid * 64 + s] = __expf(v);
    }
    {
        int row = tid >> 2, c0 = (tid & 3) * 16;
        const float* pB = xBCc + (size_t)(m0 + row) * CONV_DIM + DIN;
#pragma unroll
        for (int u = 0; u < 4; ++u) {
            f32x4 vb = *(const f32x4*)(pB + c0 + 4 * u);
            f32x4 vc = *(const f32x4*)(pB + DSTATE + c0 + 4 * u);
            short4 sb, sc;
            sb.x = f2bf(vb.x); sb.y = f2bf(vb.y); sb.z = f2bf(vb.z); sb.w = f2bf(vb.w);
            sc.x = f2bf(vc.x); sc.y = f2bf(vc.y); sc.z = f2bf(vc.z); sc.w = f2bf(vc.w);
            *(short4*)&Bb[row * LSTR + c0 + 4 * u] = sb;
            *(short4*)&Cc[row * LSTR + c0 + 4 * u] = sc;
        }
    }
    __syncthreads();
    {
        int s = tid >> 2, c0 = (tid & 3) * 16;
        float w = dtv[s];
        float w2 = __expf(Lc[63] - Lc[s]);
        const float* pX = xBCc + (size_t)(m0 + s) * CONV_DIM + h * HEADDIM;
#pragma unroll
        for (int u = 0; u < 4; ++u) {
            f32x4 v = *(const f32x4*)(pX + c0 + 4 * u);
            Xt[(c0 + 4 * u + 0) * LSTR + s] = f2bf(v.x * w);
            Xt[(c0 + 4 * u + 1) * LSTR + s] = f2bf(v.y * w);
            Xt[(c0 + 4 * u + 2) * LSTR + s] = f2bf(v.z * w);
            Xt[(c0 + 4 * u + 3) * LSTR + s] = f2bf(v.w * w);
            short4 sb = *(short4*)&Bb[s * LSTR + c0 + 4 * u];
            BwT[(c0 + 4 * u + 0) * LSTR + s] = f2bf(bf2f(sb.x) * w2);
            BwT[(c0 + 4 * u + 1) * LSTR + s] = f2bf(bf2f(sb.y) * w2);
            BwT[(c0 + 4 * u + 2) * LSTR + s] = f2bf(bf2f(sb.z) * w2);
            BwT[(c0 + 4 * u + 3) * LSTR + s] = f2bf(bf2f(sb.w) * w2);
        }
    }
    __syncthreads();

    {
        bf16x8 af[2];
#pragma unroll
        for (int kk = 0; kk < 2; ++kk)
            af[kk] = ld_frag(&Cc[(wid * 16 + lm) * LSTR + kk * 32 + lg * 8]);
#pragma unroll
        for (int j = 0; j < 4; ++j) {
            f32x4 acc = {0.f, 0.f, 0.f, 0.f};
#pragma unroll
            for (int kk = 0; kk < 2; ++kk) {
                bf16x8 bf = ld_frag(&Bb[(j * 16 + lm) * LSTR + kk * 32 + lg * 8]);
                acc = __builtin_amdgcn_mfma_f32_16x16x32_bf16(af[kk], bf, acc, 0, 0, 0);
            }
            int s = j * 16 + lm;
            float Ls = Lc[s];
#pragma unroll
            for (int r = 0; r < 4; ++r) {
                int t = wid * 16 + lg * 4 + r;
                float val = (s <= t) ? acc[r] * __expf(Lc[t] - Ls) : 0.f;
                Mm[t * LSTR + s] = f2bf(val);
            }
        }
    }
    __syncthreads();

    {
        bf16x8 am[2], aw[2];
#pragma unroll
        for (int kk = 0; kk < 2; ++kk) {
            am[kk] = ld_frag(&Mm[(wid * 16 + lm) * LSTR + kk * 32 + lg * 8]);
            aw[kk] = ld_frag(&BwT[(wid * 16 + lm) * LSTR + kk * 32 + lg * 8]);
        }
#pragma unroll
        for (int j = 0; j < 4; ++j) {
            f32x4 a1 = {0.f, 0.f, 0.f, 0.f};
            f32x4 a2 = {0.f, 0.f, 0.f, 0.f};
#pragma unroll
            for (int kk = 0; kk < 2; ++kk) {
                bf16x8 bx = ld_frag(&Xt[(j * 16 + lm) * LSTR + kk * 32 + lg * 8]);
                a1 = __builtin_amdgcn_mfma_f32_16x16x32_bf16(am[kk], bx, a1, 0, 0, 0);
                a2 = __builtin_amdgcn_mfma_f32_16x16x32_bf16(aw[kk], bx, a2, 0, 0, 0);
            }
            int p = j * 16 + lm;
#pragma unroll
            for (int r = 0; r < 4; ++r) {
                int t = wid * 16 + lg * 4 + r;
                ybuf[(size_t)(m0 + t) * DIN + h * HEADDIM + p] = a1[r];
                Sbuf[(size_t)bid * 4096 + t * 64 + p] = a2[r];
            }
        }
    }
}

// ---------------- P2: inter-chunk state recurrence ----------------
__global__ __launch_bounds__(256) void state_kernel(
    float* __restrict__ SH, const float* __restrict__ cumdecay)
{
    int bh = blockIdx.x;
    int b = bh >> 5, h = bh & 31;
    int tid = threadIdx.x;
    f32x4 H[4];
#pragma unroll
    for (int u = 0; u < 4; ++u) H[u] = {0.f, 0.f, 0.f, 0.f};
    for (int c = 0; c < NCHUNK; ++c) {
        int cid = (b * NCHUNK + c) * NH + h;
        size_t base = (size_t)cid * 4096 + (size_t)tid * 16;
        float cd = cumdecay[(size_t)cid * 64 + 63];
        f32x4 s[4];
#pragma unroll
        for (int u = 0; u < 4; ++u) s[u] = *(const f32x4*)(SH + base + u * 4);
#pragma unroll
        for (int u = 0; u < 4; ++u) *(f32x4*)(SH + base + u * 4) = H[u];
#pragma unroll
        for (int u = 0; u < 4; ++u) {
            H[u].x = cd * H[u].x + s[u].x;
            H[u].y = cd * H[u].y + s[u].y;
            H[u].z = cd * H[u].z + s[u].z;
            H[u].w = cd * H[u].w + s[u].w;
        }
    }
}

// ---------------- P3: y += exp(Lc_t) * C_t @ H_in ----------------
__global__ __launch_bounds__(256) void inter_kernel(
    const float* __restrict__ xBCc, const float* __restrict__ Hin,
    const float* __restrict__ cumdecay, float* __restrict__ ybuf)
{
    int bid = blockIdx.x;
    int h = bid & 31, c = (bid >> 5) & 31, b = bid >> 10;
    int m0 = b * SEQ + c * Q;
    int tid = threadIdx.x;
    int wid = tid >> 6, lane = tid & 63, lm = lane & 15, lg = lane >> 4;

    __shared__ __attribute__((aligned(16))) short Cc[64 * LSTR];
    __shared__ __attribute__((aligned(16))) short HT[64 * LSTR];
    __shared__ float eLc[64];

    if (tid < 64) eLc[tid] = cumdecay[(size_t)bid * 64 + tid];
    {
        int row = tid >> 2, c0 = (tid & 3) * 16;
        const float* pC = xBCc + (size_t)(m0 + row) * CONV_DIM + DIN + DSTATE;
        const float* pH = Hin + (size_t)bid * 4096 + row * 64;
#pragma unroll
        for (int u = 0; u < 4; ++u) {
            f32x4 vc = *(const f32x4*)(pC + c0 + 4 * u);
            short4 sc;
            sc.x = f2bf(vc.x); sc.y = f2bf(vc.y); sc.z = f2bf(vc.z); sc.w = f2bf(vc.w);
            *(short4*)&Cc[row * LSTR + c0 + 4 * u] = sc;
            f32x4 vh = *(const f32x4*)(pH + c0 + 4 * u);
            HT[(c0 + 4 * u + 0) * LSTR + row] = f2bf(vh.x);
            HT[(c0 + 4 * u + 1) * LSTR + row] = f2bf(vh.y);
            HT[(c0 + 4 * u + 2) * LSTR + row] = f2bf(vh.z);
            HT[(c0 + 4 * u + 3) * LSTR + row] = f2bf(vh.w);
        }
    }
    __syncthreads();

    bf16x8 af[2];
#pragma unroll
    for (int kk = 0; kk < 2; ++kk)
        af[kk] = ld_frag(&Cc[(wid * 16 + lm) * LSTR + kk * 32 + lg * 8]);
#pragma unroll
    for (int j = 0; j < 4; ++j) {
        f32x4 acc = {0.f, 0.f, 0.f, 0.f};
#pragma unroll
        for (int kk = 0; kk < 2; ++kk) {
            bf16x8 bh_ = ld_frag(&HT[(j * 16 + lm) * LSTR + kk * 32 + lg * 8]);
            acc = __builtin_amdgcn_mfma_f32_16x16x32_bf16(af[kk], bh_, acc, 0, 0, 0);
        }
        int p = j * 16 + lm;
#pragma unroll
        for (int r = 0; r < 4; ++r) {
            int t = wid * 16 + lg * 4 + r;
            size_t ya = (size_t)(m0 + t) * DIN + h * HEADDIM + p;
            ybuf[ya] += eLc[t] * acc[r];
        }
    }
}

// ---------------- ybf = bf16(rmsnorm((y + D*x) * silu(z), norm_w)) ----------------
__global__ __launch_bounds__(256) void norm1_kernel(
    const float* __restrict__ zx, const float* __restrict__ xBCc,
    const float* __restrict__ Dp, const float* __restrict__ y,
    short* __restrict__ ybf, const float* __restrict__ w)
{
    int m = blockIdx.x;
    int t = threadIdx.x;
    const float* zr = zx + (size_t)m * DPROJ;
    const float* xr = xBCc + (size_t)m * CONV_DIM;
    const float* yr = y + (size_t)m * DIN;
    float vals[8];
    float ss = 0.f;
#pragma unroll
    for (int j = 0; j < 8; ++j) {
        int i = j * 256 + t;
        float v = (yr[i] + Dp[i >> 6] * xr[i]) * silu_f(zr[i]);
        vals[j] = v;
        ss += v * v;
    }
#pragma unroll
    for (int o = 32; o >= 1; o >>= 1) ss += __shfl_xor(ss, o);
    __shared__ float wsum[4];
    if ((t & 63) == 0) wsum[t >> 6] = ss;
    __syncthreads();
    float tot = wsum[0] + wsum[1] + wsum[2] + wsum[3];
    float scale = rsqrtf(tot / (float)DIN + EPS);
#pragma unroll
    for (int j = 0; j < 8; ++j) {
        int i = j * 256 + t;
        ybf[(size_t)m * DIN + i] = f2bf(vals[j] * scale * w[i]);
    }
}

// ---------------- hnbf = bf16(rmsnorm(h, rms_w)) ----------------
__global__ __launch_bounds__(256) void norm2_kernel(
    const float* __restrict__ hb, short* __restrict__ hnbf, const float* __restrict__ w)
{
    int m = blockIdx.x;
    int t = threadIdx.x;
    const float* hr = hb + (size_t)m * DMODEL;
    float vals[4];
    float ss = 0.f;
#pragma unroll
    for (int j = 0; j < 4; ++j) {
        int i = j * 256 + t;
        float v = hr[i];
        vals[j] = v;
        ss += v * v;
    }
#pragma unroll
    for (int o = 32; o >= 1; o >>= 1) ss += __shfl_xor(ss, o);
    __shared__ float wsum[4];
    if ((t & 63) == 0) wsum[t >> 6] = ss;
    __syncthreads();
    float tot = wsum[0] + wsum[1] + wsum[2] + wsum[3];
    float scale = rsqrtf(tot / (float)DMODEL + EPS);
#pragma unroll
    for (int j = 0; j < 4; ++j) {
        int i = j * 256 + t;
        hnbf[(size_t)m * DMODEL + i] = f2bf(vals[j] * scale * w[i]);
    }
}

extern "C" void kernel_launch(void* const* d_in, const int* in_sizes, int n_in,
                              void* d_out, int out_size, void* d_ws, size_t ws_size,
                              hipStream_t stream) {
    const float* x       = (const float*)d_in[0];
    const float* W_in    = (const float*)d_in[1];
    const float* conv_w  = (const float*)d_in[2];
    const float* conv_b  = (const float*)d_in[3];
    const float* dt_bias = (const float*)d_in[4];
    const float* A_log   = (const float*)d_in[5];
    const float* D_param = (const float*)d_in[6];
    const float* norm_w  = (const float*)d_in[7];
    const float* W_out   = (const float*)d_in[8];
    const float* rms_w   = (const float*)d_in[9];
    const float* mlp_w1  = (const float*)d_in[10];
    const float* mlp_b1  = (const float*)d_in[11];
    const float* mlp_w2  = (const float*)d_in[12];
    const float* mlp_b2  = (const float*)d_in[13];
    float* out = (float*)d_out;

    float* ws       = (float*)d_ws;
    float* zx       = ws;
    float* xBCc     = zx + (size_t)TOKENS * DPROJ;
    float* dtb      = xBCc + (size_t)TOKENS * CONV_DIM;
    float* ldab     = dtb + (size_t)TOKENS * NH;
    float* cumdecay = ldab + (size_t)TOKENS * NH;
    float* ybuf     = cumdecay + (size_t)TOKENS * NH;
    float* SH       = ybuf + (size_t)TOKENS * DIN;
    float* bfarea   = SH + (size_t)NCH * 4096;

    short* xbf   = (short*)ybuf;
    short* midbf = (short*)ybuf;
    float* hbuf  = SH;
    short* hnbf  = (short*)(SH + (size_t)TOKENS * DMODEL);

    short* ybf   = (short*)bfarea;
    short* WinT  = ybf + (size_t)TOKENS * DIN;
    short* WoutT = WinT + (size_t)NPAD_IN * DMODEL;
    short* w1T   = WoutT + (size_t)DMODEL * DIN;
    short* w2T   = w1T + (size_t)MLP_INNER * DMODEL;

    dim3 blk(256);

    // 0. conversions / weight transposes
    cvt_kernel<<<dim3(TOKENS * DMODEL / 4 / 256), blk, 0, stream>>>(x, xbf, TOKENS * DMODEL / 4);
    transpose_kernel<<<dim3(NPAD_IN / 32, DMODEL / 32), blk, 0, stream>>>(W_in, WinT, DMODEL, DPROJ);
    transpose_kernel<<<dim3(DMODEL / 32, DIN / 32), blk, 0, stream>>>(W_out, WoutT, DIN, DMODEL);
    transpose_kernel<<<dim3(MLP_INNER / 32, DMODEL / 32), blk, 0, stream>>>(mlp_w1, w1T, DMODEL, MLP_INNER);
    transpose_kernel<<<dim3(DMODEL / 32, MLP_INNER / 32), blk, 0, stream>>>(mlp_w2, w2T, MLP_INNER, DMODEL);

    // 1. zx = x @ W_in
    gemm_bf16_kernel<0><<<dim3(NPAD_IN / 128, TOKENS / 128), blk, 0, stream>>>(
        xbf, WinT, zx, nullptr, nullptr, TOKENS, DPROJ, DMODEL);
    // 2. conv + bias + silu
    conv_kernel<<<dim3(TOKENS, (CONV_DIM / 4 + 255) / 256), blk, 0, stream>>>(
        zx, conv_w, conv_b, xBCc);
    // 3. dt / ldA
    dt_kernel<<<dim3(TOKENS * NH / 256), blk, 0, stream>>>(zx, dt_bias, A_log, dtb, ldab);
    // 4. SSD
    chunk_kernel<<<dim3(NCH), blk, 0, stream>>>(xBCc, dtb, ldab, ybuf, SH, cumdecay);
    state_kernel<<<dim3(BATCH * NH), blk, 0, stream>>>(SH, cumdecay);
    inter_kernel<<<dim3(NCH), blk, 0, stream>>>(xBCc, SH, cumdecay, ybuf);
    // 5. ybf = bf16(rmsnorm((y + D*x) * silu(z)))
    norm1_kernel<<<dim3(TOKENS), blk, 0, stream>>>(zx, xBCc, D_param, ybuf, ybf, norm_w);
    // 6. h = x + ybf @ W_out
    gemm_bf16_kernel<3><<<dim3(DMODEL / 128, TOKENS / 128), blk, 0, stream>>>(
        ybf, WoutT, hbuf, nullptr, x, TOKENS, DMODEL, DIN);
    // 7. hnbf = bf16(rmsnorm(h))
    norm2_kernel<<<dim3(TOKENS), blk, 0, stream>>>(hbuf, hnbf, rms_w);
    // 8. midbf = bf16(silu(hnbf @ mlp_w1 + b1))
    gemm_bf16_kernel<1><<<dim3(MLP_INNER / 128, TOKENS / 128), blk, 0, stream>>>(
        hnbf, w1T, midbf, mlp_b1, nullptr, TOKENS, MLP_INNER, DMODEL);
    // 9. out = h + midbf @ mlp_w2 + b2
    gemm_bf16_kernel<2><<<dim3(DMODEL / 128, TOKENS / 128), blk, 0, stream>>>(
        midbf, w2T, out, mlp_b2, hbuf, TOKENS, DMODEL, MLP_INNER);
}

// Round 6
// 473.368 us; speedup vs baseline: 1.2409x; 1.1104x over previous
//
#include <hip/hip_runtime.h>
#include <hip/hip_bf16.h>
#include <cstdint>
#include <cstddef>

#define BATCH 2
#define SEQ 2048
#define DMODEL 1024
#define DIN 2048
#define NH 32
#define HEADDIM 64
#define DSTATE 64
#define DCONV 4
#define CONV_DIM (DIN + 2 * DSTATE)          // 2176
#define DPROJ (2 * DIN + 2 * DSTATE + NH)    // 4256
#define MLP_INNER 4096
#define TOKENS (BATCH * SEQ)                 // 4096
#define EPS 1e-5f
#define Q 64
#define NCHUNK (SEQ / Q)                     // 32
#define NCH (BATCH * NCHUNK * NH)            // 2048 chunk-heads
#define LSTR 72
#define NPAD_IN 4352                          // DPROJ padded to 34*128

typedef __attribute__((ext_vector_type(8))) short short8;
typedef __attribute__((ext_vector_type(8))) __bf16 bf16x8;
typedef __attribute__((ext_vector_type(4))) float f32x4;

__device__ inline short f2bf(float f) {
    unsigned u = __builtin_bit_cast(unsigned, f);
    u = (u + 0x7FFFu + ((u >> 16) & 1u)) >> 16;
    return (short)u;
}
__device__ inline float bf2f(short s) {
    unsigned u = ((unsigned)(unsigned short)s) << 16;
    return __builtin_bit_cast(float, u);
}
__device__ inline float silu_f(float x) { return x / (1.f + __expf(-x)); }

__device__ inline bf16x8 ld_frag(const short* p) {
    short8 s = *(const short8*)p;
    return __builtin_bit_cast(bf16x8, s);
}

__device__ inline void glds16(const short* g, short* l) {
    __builtin_amdgcn_global_load_lds(
        (const __attribute__((address_space(1))) void*)g,
        (__attribute__((address_space(3))) void*)l, 16, 0, 0);
}

// ---------------- bf16 GEMM, m97 structure + LDS double-buffer + XCD swizzle ----
// MODE 0: f32 C = AB; 1: bf16 C = silu(AB+bias); 2: f32 C = AB+bias+res; 3: f32 C = AB+res
template <int MODE>
__global__ __launch_bounds__(256, 4) void gemm_bf16_kernel(
    const short* __restrict__ A, const short* __restrict__ BT,
    void* __restrict__ Cout, const float* __restrict__ bias,
    const float* __restrict__ res, int M, int N, int K)
{
    const int tid  = threadIdx.x;
    const int wid  = tid >> 6;
    const int lane = tid & 63;
    const int lm   = lane & 15;
    const int lg   = lane >> 4;

    const int nb  = gridDim.x * gridDim.y;
    const int bid = blockIdx.y * gridDim.x + blockIdx.x;
    const int per = nb >> 3;
    const int nid = (bid & 7) * per + (bid >> 3);
    const int m0  = (nid / gridDim.x) * 128;
    const int n0  = (nid % gridDim.x) * 128;

    __shared__ __attribute__((aligned(16))) short Al0[128 * 32];
    __shared__ __attribute__((aligned(16))) short Al1[128 * 32];
    __shared__ __attribute__((aligned(16))) short Bl0[128 * 32];
    __shared__ __attribute__((aligned(16))) short Bl1[128 * 32];

    f32x4 acc[4][4];
#pragma unroll
    for (int i = 0; i < 4; ++i)
#pragma unroll
        for (int j = 0; j < 4; ++j) acc[i][j] = {0.f, 0.f, 0.f, 0.f};

    const int wm = (wid >> 1) * 64;
    const int wn = (wid & 1) * 64;

    const int srow = lane >> 2;
    const int scol = (lane & 3) * 8;
    const short* Ag = A  + (size_t)(m0 + wid * 32 + srow) * K + scol;
    const short* Bg = BT + (size_t)(n0 + wid * 32 + srow) * K + scol;

    const int niter = K >> 5;
    {
        short* al = Al0 + wid * 1024;
        short* bl = Bl0 + wid * 1024;
        glds16(Ag, al);           glds16(Ag + 16 * K, al + 512);
        glds16(Bg, bl);           glds16(Bg + 16 * K, bl + 512);
    }

    for (int i = 0; i < niter; ++i) {
        __syncthreads();
        const short* Ac = (i & 1) ? Al1 : Al0;
        const short* Bc = (i & 1) ? Bl1 : Bl0;
        if (i + 1 < niter) {
            int kt = (i + 1) << 5;
            short* al = ((i & 1) ? Al0 : Al1) + wid * 1024;
            short* bl = ((i & 1) ? Bl0 : Bl1) + wid * 1024;
            glds16(Ag + kt, al);          glds16(Ag + 16 * K + kt, al + 512);
            glds16(Bg + kt, bl);          glds16(Bg + 16 * K + kt, bl + 512);
        }

        bf16x8 af[4], bf[4];
#pragma unroll
        for (int ii = 0; ii < 4; ++ii)
            af[ii] = ld_frag(&Ac[(wm + ii * 16 + lm) * 32 + lg * 8]);
#pragma unroll
        for (int j = 0; j < 4; ++j)
            bf[j] = ld_frag(&Bc[(wn + j * 16 + lm) * 32 + lg * 8]);
#pragma unroll
        for (int ii = 0; ii < 4; ++ii)
#pragma unroll
            for (int j = 0; j < 4; ++j)
                acc[ii][j] = __builtin_amdgcn_mfma_f32_16x16x32_bf16(af[ii], bf[j], acc[ii][j], 0, 0, 0);
    }

#pragma unroll
    for (int i = 0; i < 4; ++i) {
#pragma unroll
        for (int j = 0; j < 4; ++j) {
            int col = n0 + wn + j * 16 + lm;
            if (col >= N) continue;
            float bv = (MODE == 1 || MODE == 2) ? bias[col] : 0.f;
#pragma unroll
            for (int r = 0; r < 4; ++r) {
                int row = m0 + wm + i * 16 + lg * 4 + r;
                float v = acc[i][j][r];
                if (MODE == 1) {
                    ((short*)Cout)[(size_t)row * N + col] = f2bf(silu_f(v + bv));
                } else {
                    if (MODE == 2) v = v + bv + res[(size_t)row * N + col];
                    if (MODE == 3) v = v + res[(size_t)row * N + col];
                    ((float*)Cout)[(size_t)row * N + col] = v;
                }
            }
        }
    }
}

// ---------------- f32 -> bf16 convert ----------------
__global__ __launch_bounds__(256) void cvt_kernel(
    const float* __restrict__ src, short* __restrict__ dst, int n4)
{
    int i = (blockIdx.x * 256 + threadIdx.x);
    if (i >= n4) return;
    f32x4 v = *(const f32x4*)(src + (size_t)i * 4);
    short4 o;
    o.x = f2bf(v.x); o.y = f2bf(v.y); o.z = f2bf(v.z); o.w = f2bf(v.w);
    *(short4*)(dst + (size_t)i * 4) = o;
}

// ---------------- W [K][N] f32 -> WT [Npad][K] bf16 ----------------
__global__ __launch_bounds__(256) void transpose_kernel(
    const float* __restrict__ src, short* __restrict__ dst, int K, int N)
{
    __shared__ float t[32][33];
    int bx = blockIdx.x, by = blockIdx.y;
    int col = threadIdx.x & 31, row8 = threadIdx.x >> 5;
    int gn = bx * 32 + col;
#pragma unroll
    for (int r = 0; r < 4; ++r) {
        int gk = by * 32 + row8 + r * 8;
        t[row8 + r * 8][col] = (gn < N) ? src[(size_t)gk * N + gn] : 0.f;
    }
    __syncthreads();
#pragma unroll
    for (int r = 0; r < 4; ++r) {
        int n = bx * 32 + row8 + r * 8;
        dst[(size_t)n * K + by * 32 + col] = f2bf(t[col][row8 + r * 8]);
    }
}

// ---------------- depthwise causal conv (k=4) + bias + silu, token-blocked ----
// Each thread: 4 channels (one f32x4) x 8 consecutive tokens, 11-row sliding
// window in registers. Read amplification 11/8 vs 4x in the naive version.
#define CTOK 8
__global__ __launch_bounds__(256) void conv_kernel(
    const float* __restrict__ zx, const float* __restrict__ cw,
    const float* __restrict__ cb, float* __restrict__ xBCc)
{
    int c4 = blockIdx.y * 256 + threadIdx.x;
    if (c4 >= CONV_DIM / 4) return;
    int c  = c4 * 4;
    int m0 = blockIdx.x * CTOK;          // 8-token group; never straddles batch
    int l0 = m0 & (SEQ - 1);

    const float* base = zx + (size_t)m0 * DPROJ + DIN + c;
    f32x4 win[CTOK + 3];
#pragma unroll
    for (int j = 0; j < CTOK + 3; ++j) {
        int off = j - 3;                  // row m0+off
        if (l0 + off >= 0)
            win[j] = *(const f32x4*)(base + (ptrdiff_t)off * DPROJ);
        else
            win[j] = {0.f, 0.f, 0.f, 0.f};
    }
    // weights: 4 channels x 4 taps, contiguous 64B
    f32x4 w0 = *(const f32x4*)(cw + (c + 0) * DCONV);
    f32x4 w1 = *(const f32x4*)(cw + (c + 1) * DCONV);
    f32x4 w2 = *(const f32x4*)(cw + (c + 2) * DCONV);
    f32x4 w3 = *(const f32x4*)(cw + (c + 3) * DCONV);
    f32x4 bb = *(const f32x4*)(cb + c);

    float* outp = xBCc + (size_t)m0 * CONV_DIM + c;
#pragma unroll
    for (int t = 0; t < CTOK; ++t) {
        f32x4 a = {bb.x, bb.y, bb.z, bb.w};
#pragma unroll
        for (int j = 0; j < DCONV; ++j) {
            f32x4 v = win[t + j];
            a.x += v.x * w0[j];
            a.y += v.y * w1[j];
            a.z += v.z * w2[j];
            a.w += v.w * w3[j];
        }
        f32x4 o;
        o.x = silu_f(a.x); o.y = silu_f(a.y); o.z = silu_f(a.z); o.w = silu_f(a.w);
        *(f32x4*)(outp + (size_t)t * CONV_DIM) = o;
    }
}

// ---------------- dt = softplus(dt_raw + bias); ldA = A * dt ----------------
__global__ __launch_bounds__(256) void dt_kernel(
    const float* __restrict__ zx, const float* __restrict__ dt_bias,
    const float* __restrict__ A_log, float* __restrict__ dtb, float* __restrict__ ldab)
{
    int idx = blockIdx.x * 256 + threadIdx.x;
    if (idx >= TOKENS * NH) return;
    int hh = idx & (NH - 1);
    int m  = idx >> 5;
    float v  = zx[(size_t)m * DPROJ + DIN + CONV_DIM + hh] + dt_bias[hh];
    float dt = (v > 20.f) ? v : log1pf(__expf(v));
    dtb[idx]  = dt;
    ldab[idx] = -__expf(A_log[hh]) * dt;
}

// ---------------- P1: intra-chunk SSD ----------------
__global__ __launch_bounds__(256) void chunk_kernel(
    const float* __restrict__ xBCc, const float* __restrict__ dtb,
    const float* __restrict__ ldab, float* __restrict__ ybuf,
    float* __restrict__ Sbuf, float* __restrict__ cumdecay)
{
    int bid = blockIdx.x;
    int h = bid & 31, c = (bid >> 5) & 31, b = bid >> 10;
    int m0 = b * SEQ + c * Q;
    int tid = threadIdx.x;
    int wid = tid >> 6, lane = tid & 63, lm = lane & 15, lg = lane >> 4;

    __shared__ __attribute__((aligned(16))) short Cc[64 * LSTR];
    __shared__ __attribute__((aligned(16))) short Bb[64 * LSTR];
    __shared__ __attribute__((aligned(16))) short BwT[64 * LSTR];
    __shared__ __attribute__((aligned(16))) short Xt[64 * LSTR];
    __shared__ __attribute__((aligned(16))) short Mm[64 * LSTR];
    __shared__ float Lc[64], dtv[64];

    if (tid < 64) {
        int s = tid;
        size_t ix = (size_t)(m0 + s) * NH + h;
        float ld = ldab[ix];
        float dt = dtb[ix];
        float v = ld;
#pragma unroll
        for (int off = 1; off < 64; off <<= 1) {
            float o = __shfl_up(v, off);
            if (s >= off) v += o;
        }
        Lc[s] = v;
        dtv[s] = dt;
        cumdecay[(size_t)bid * 64 + s] = __expf(v);
    }
    {
        int row = tid >> 2, c0 = (tid & 3) * 16;
        const float* pB = xBCc + (size_t)(m0 + row) * CONV_DIM + DIN;
#pragma unroll
        for (int u = 0; u < 4; ++u) {
            f32x4 vb = *(const f32x4*)(pB + c0 + 4 * u);
            f32x4 vc = *(const f32x4*)(pB + DSTATE + c0 + 4 * u);
            short4 sb, sc;
            sb.x = f2bf(vb.x); sb.y = f2bf(vb.y); sb.z = f2bf(vb.z); sb.w = f2bf(vb.w);
            sc.x = f2bf(vc.x); sc.y = f2bf(vc.y); sc.z = f2bf(vc.z); sc.w = f2bf(vc.w);
            *(short4*)&Bb[row * LSTR + c0 + 4 * u] = sb;
            *(short4*)&Cc[row * LSTR + c0 + 4 * u] = sc;
        }
    }
    __syncthreads();
    {
        int s = tid >> 2, c0 = (tid & 3) * 16;
        float w = dtv[s];
        float w2 = __expf(Lc[63] - Lc[s]);
        const float* pX = xBCc + (size_t)(m0 + s) * CONV_DIM + h * HEADDIM;
#pragma unroll
        for (int u = 0; u < 4; ++u) {
            f32x4 v = *(const f32x4*)(pX + c0 + 4 * u);
            Xt[(c0 + 4 * u + 0) * LSTR + s] = f2bf(v.x * w);
            Xt[(c0 + 4 * u + 1) * LSTR + s] = f2bf(v.y * w);
            Xt[(c0 + 4 * u + 2) * LSTR + s] = f2bf(v.z * w);
            Xt[(c0 + 4 * u + 3) * LSTR + s] = f2bf(v.w * w);
            short4 sb = *(short4*)&Bb[s * LSTR + c0 + 4 * u];
            BwT[(c0 + 4 * u + 0) * LSTR + s] = f2bf(bf2f(sb.x) * w2);
            BwT[(c0 + 4 * u + 1) * LSTR + s] = f2bf(bf2f(sb.y) * w2);
            BwT[(c0 + 4 * u + 2) * LSTR + s] = f2bf(bf2f(sb.z) * w2);
            BwT[(c0 + 4 * u + 3) * LSTR + s] = f2bf(bf2f(sb.w) * w2);
        }
    }
    __syncthreads();

    {
        bf16x8 af[2];
#pragma unroll
        for (int kk = 0; kk < 2; ++kk)
            af[kk] = ld_frag(&Cc[(wid * 16 + lm) * LSTR + kk * 32 + lg * 8]);
#pragma unroll
        for (int j = 0; j < 4; ++j) {
            f32x4 acc = {0.f, 0.f, 0.f, 0.f};
#pragma unroll
            for (int kk = 0; kk < 2; ++kk) {
                bf16x8 bf = ld_frag(&Bb[(j * 16 + lm) * LSTR + kk * 32 + lg * 8]);
                acc = __builtin_amdgcn_mfma_f32_16x16x32_bf16(af[kk], bf, acc, 0, 0, 0);
            }
            int s = j * 16 + lm;
            float Ls = Lc[s];
#pragma unroll
            for (int r = 0; r < 4; ++r) {
                int t = wid * 16 + lg * 4 + r;
                float val = (s <= t) ? acc[r] * __expf(Lc[t] - Ls) : 0.f;
                Mm[t * LSTR + s] = f2bf(val);
            }
        }
    }
    __syncthreads();

    {
        bf16x8 am[2], aw[2];
#pragma unroll
        for (int kk = 0; kk < 2; ++kk) {
            am[kk] = ld_frag(&Mm[(wid * 16 + lm) * LSTR + kk * 32 + lg * 8]);
            aw[kk] = ld_frag(&BwT[(wid * 16 + lm) * LSTR + kk * 32 + lg * 8]);
        }
#pragma unroll
        for (int j = 0; j < 4; ++j) {
            f32x4 a1 = {0.f, 0.f, 0.f, 0.f};
            f32x4 a2 = {0.f, 0.f, 0.f, 0.f};
#pragma unroll
            for (int kk = 0; kk < 2; ++kk) {
                bf16x8 bx = ld_frag(&Xt[(j * 16 + lm) * LSTR + kk * 32 + lg * 8]);
                a1 = __builtin_amdgcn_mfma_f32_16x16x32_bf16(am[kk], bx, a1, 0, 0, 0);
                a2 = __builtin_amdgcn_mfma_f32_16x16x32_bf16(aw[kk], bx, a2, 0, 0, 0);
            }
            int p = j * 16 + lm;
#pragma unroll
            for (int r = 0; r < 4; ++r) {
                int t = wid * 16 + lg * 4 + r;
                ybuf[(size_t)(m0 + t) * DIN + h * HEADDIM + p] = a1[r];
                Sbuf[(size_t)bid * 4096 + t * 64 + p] = a2[r];
            }
        }
    }
}

// ---------------- P2: inter-chunk state recurrence ----------------
__global__ __launch_bounds__(256) void state_kernel(
    float* __restrict__ SH, const float* __restrict__ cumdecay)
{
    int bh = blockIdx.x;
    int b = bh >> 5, h = bh & 31;
    int tid = threadIdx.x;
    f32x4 H[4];
#pragma unroll
    for (int u = 0; u < 4; ++u) H[u] = {0.f, 0.f, 0.f, 0.f};
    for (int c = 0; c < NCHUNK; ++c) {
        int cid = (b * NCHUNK + c) * NH + h;
        size_t base = (size_t)cid * 4096 + (size_t)tid * 16;
        float cd = cumdecay[(size_t)cid * 64 + 63];
        f32x4 s[4];
#pragma unroll
        for (int u = 0; u < 4; ++u) s[u] = *(const f32x4*)(SH + base + u * 4);
#pragma unroll
        for (int u = 0; u < 4; ++u) *(f32x4*)(SH + base + u * 4) = H[u];
#pragma unroll
        for (int u = 0; u < 4; ++u) {
            H[u].x = cd * H[u].x + s[u].x;
            H[u].y = cd * H[u].y + s[u].y;
            H[u].z = cd * H[u].z + s[u].z;
            H[u].w = cd * H[u].w + s[u].w;
        }
    }
}

// ---------------- P3: y += exp(Lc_t) * C_t @ H_in ----------------
__global__ __launch_bounds__(256) void inter_kernel(
    const float* __restrict__ xBCc, const float* __restrict__ Hin,
    const float* __restrict__ cumdecay, float* __restrict__ ybuf)
{
    int bid = blockIdx.x;
    int h = bid & 31, c = (bid >> 5) & 31, b = bid >> 10;
    int m0 = b * SEQ + c * Q;
    int tid = threadIdx.x;
    int wid = tid >> 6, lane = tid & 63, lm = lane & 15, lg = lane >> 4;

    __shared__ __attribute__((aligned(16))) short Cc[64 * LSTR];
    __shared__ __attribute__((aligned(16))) short HT[64 * LSTR];
    __shared__ float eLc[64];

    if (tid < 64) eLc[tid] = cumdecay[(size_t)bid * 64 + tid];
    {
        int row = tid >> 2, c0 = (tid & 3) * 16;
        const float* pC = xBCc + (size_t)(m0 + row) * CONV_DIM + DIN + DSTATE;
        const float* pH = Hin + (size_t)bid * 4096 + row * 64;
#pragma unroll
        for (int u = 0; u < 4; ++u) {
            f32x4 vc = *(const f32x4*)(pC + c0 + 4 * u);
            short4 sc;
            sc.x = f2bf(vc.x); sc.y = f2bf(vc.y); sc.z = f2bf(vc.z); sc.w = f2bf(vc.w);
            *(short4*)&Cc[row * LSTR + c0 + 4 * u] = sc;
            f32x4 vh = *(const f32x4*)(pH + c0 + 4 * u);
            HT[(c0 + 4 * u + 0) * LSTR + row] = f2bf(vh.x);
            HT[(c0 + 4 * u + 1) * LSTR + row] = f2bf(vh.y);
            HT[(c0 + 4 * u + 2) * LSTR + row] = f2bf(vh.z);
            HT[(c0 + 4 * u + 3) * LSTR + row] = f2bf(vh.w);
        }
    }
    __syncthreads();

    bf16x8 af[2];
#pragma unroll
    for (int kk = 0; kk < 2; ++kk)
        af[kk] = ld_frag(&Cc[(wid * 16 + lm) * LSTR + kk * 32 + lg * 8]);
#pragma unroll
    for (int j = 0; j < 4; ++j) {
        f32x4 acc = {0.f, 0.f, 0.f, 0.f};
#pragma unroll
        for (int kk = 0; kk < 2; ++kk) {
            bf16x8 bh_ = ld_frag(&HT[(j * 16 + lm) * LSTR + kk * 32 + lg * 8]);
            acc = __builtin_amdgcn_mfma_f32_16x16x32_bf16(af[kk], bh_, acc, 0, 0, 0);
        }
        int p = j * 16 + lm;
#pragma unroll
        for (int r = 0; r < 4; ++r) {
            int t = wid * 16 + lg * 4 + r;
            size_t ya = (size_t)(m0 + t) * DIN + h * HEADDIM + p;
            ybuf[ya] += eLc[t] * acc[r];
        }
    }
}

// ---------------- ybf = bf16(rmsnorm((y + D*x) * silu(z), norm_w)) ----------------
__global__ __launch_bounds__(256) void norm1_kernel(
    const float* __restrict__ zx, const float* __restrict__ xBCc,
    const float* __restrict__ Dp, const float* __restrict__ y,
    short* __restrict__ ybf, const float* __restrict__ w)
{
    int m = blockIdx.x;
    int t = threadIdx.x;
    const float* zr = zx + (size_t)m * DPROJ;
    const float* xr = xBCc + (size_t)m * CONV_DIM;
    const float* yr = y + (size_t)m * DIN;
    float vals[8];
    float ss = 0.f;
#pragma unroll
    for (int j = 0; j < 8; ++j) {
        int i = j * 256 + t;
        float v = (yr[i] + Dp[i >> 6] * xr[i]) * silu_f(zr[i]);
        vals[j] = v;
        ss += v * v;
    }
#pragma unroll
    for (int o = 32; o >= 1; o >>= 1) ss += __shfl_xor(ss, o);
    __shared__ float wsum[4];
    if ((t & 63) == 0) wsum[t >> 6] = ss;
    __syncthreads();
    float tot = wsum[0] + wsum[1] + wsum[2] + wsum[3];
    float scale = rsqrtf(tot / (float)DIN + EPS);
#pragma unroll
    for (int j = 0; j < 8; ++j) {
        int i = j * 256 + t;
        ybf[(size_t)m * DIN + i] = f2bf(vals[j] * scale * w[i]);
    }
}

// ---------------- hnbf = bf16(rmsnorm(h, rms_w)) ----------------
__global__ __launch_bounds__(256) void norm2_kernel(
    const float* __restrict__ hb, short* __restrict__ hnbf, const float* __restrict__ w)
{
    int m = blockIdx.x;
    int t = threadIdx.x;
    const float* hr = hb + (size_t)m * DMODEL;
    float vals[4];
    float ss = 0.f;
#pragma unroll
    for (int j = 0; j < 4; ++j) {
        int i = j * 256 + t;
        float v = hr[i];
        vals[j] = v;
        ss += v * v;
    }
#pragma unroll
    for (int o = 32; o >= 1; o >>= 1) ss += __shfl_xor(ss, o);
    __shared__ float wsum[4];
    if ((t & 63) == 0) wsum[t >> 6] = ss;
    __syncthreads();
    float tot = wsum[0] + wsum[1] + wsum[2] + wsum[3];
    float scale = rsqrtf(tot / (float)DMODEL + EPS);
#pragma unroll
    for (int j = 0; j < 4; ++j) {
        int i = j * 256 + t;
        hnbf[(size_t)m * DMODEL + i] = f2bf(vals[j] * scale * w[i]);
    }
}

extern "C" void kernel_launch(void* const* d_in, const int* in_sizes, int n_in,
                              void* d_out, int out_size, void* d_ws, size_t ws_size,
                              hipStream_t stream) {
    const float* x       = (const float*)d_in[0];
    const float* W_in    = (const float*)d_in[1];
    const float* conv_w  = (const float*)d_in[2];
    const float* conv_b  = (const float*)d_in[3];
    const float* dt_bias = (const float*)d_in[4];
    const float* A_log   = (const float*)d_in[5];
    const float* D_param = (const float*)d_in[6];
    const float* norm_w  = (const float*)d_in[7];
    const float* W_out   = (const float*)d_in[8];
    const float* rms_w   = (const float*)d_in[9];
    const float* mlp_w1  = (const float*)d_in[10];
    const float* mlp_b1  = (const float*)d_in[11];
    const float* mlp_w2  = (const float*)d_in[12];
    const float* mlp_b2  = (const float*)d_in[13];
    float* out = (float*)d_out;

    float* ws       = (float*)d_ws;
    float* zx       = ws;
    float* xBCc     = zx + (size_t)TOKENS * DPROJ;
    float* dtb      = xBCc + (size_t)TOKENS * CONV_DIM;
    float* ldab     = dtb + (size_t)TOKENS * NH;
    float* cumdecay = ldab + (size_t)TOKENS * NH;
    float* ybuf     = cumdecay + (size_t)TOKENS * NH;
    float* SH       = ybuf + (size_t)TOKENS * DIN;
    float* bfarea   = SH + (size_t)NCH * 4096;

    short* xbf   = (short*)ybuf;
    short* midbf = (short*)ybuf;
    float* hbuf  = SH;
    short* hnbf  = (short*)(SH + (size_t)TOKENS * DMODEL);

    short* ybf   = (short*)bfarea;
    short* WinT  = ybf + (size_t)TOKENS * DIN;
    short* WoutT = WinT + (size_t)NPAD_IN * DMODEL;
    short* w1T   = WoutT + (size_t)DMODEL * DIN;
    short* w2T   = w1T + (size_t)MLP_INNER * DMODEL;

    dim3 blk(256);

    // 0. conversions / weight transposes
    cvt_kernel<<<dim3(TOKENS * DMODEL / 4 / 256), blk, 0, stream>>>(x, xbf, TOKENS * DMODEL / 4);
    transpose_kernel<<<dim3(NPAD_IN / 32, DMODEL / 32), blk, 0, stream>>>(W_in, WinT, DMODEL, DPROJ);
    transpose_kernel<<<dim3(DMODEL / 32, DIN / 32), blk, 0, stream>>>(W_out, WoutT, DIN, DMODEL);
    transpose_kernel<<<dim3(MLP_INNER / 32, DMODEL / 32), blk, 0, stream>>>(mlp_w1, w1T, DMODEL, MLP_INNER);
    transpose_kernel<<<dim3(DMODEL / 32, MLP_INNER / 32), blk, 0, stream>>>(mlp_w2, w2T, MLP_INNER, DMODEL);

    // 1. zx = x @ W_in
    gemm_bf16_kernel<0><<<dim3(NPAD_IN / 128, TOKENS / 128), blk, 0, stream>>>(
        xbf, WinT, zx, nullptr, nullptr, TOKENS, DPROJ, DMODEL);
    // 2. conv + bias + silu (token-blocked)
    conv_kernel<<<dim3(TOKENS / CTOK, (CONV_DIM / 4 + 255) / 256), blk, 0, stream>>>(
        zx, conv_w, conv_b, xBCc);
    // 3. dt / ldA
    dt_kernel<<<dim3(TOKENS * NH / 256), blk, 0, stream>>>(zx, dt_bias, A_log, dtb, ldab);
    // 4. SSD
    chunk_kernel<<<dim3(NCH), blk, 0, stream>>>(xBCc, dtb, ldab, ybuf, SH, cumdecay);
    state_kernel<<<dim3(BATCH * NH), blk, 0, stream>>>(SH, cumdecay);
    inter_kernel<<<dim3(NCH), blk, 0, stream>>>(xBCc, SH, cumdecay, ybuf);
    // 5. ybf = bf16(rmsnorm((y + D*x) * silu(z)))
    norm1_kernel<<<dim3(TOKENS), blk, 0, stream>>>(zx, xBCc, D_param, ybuf, ybf, norm_w);
    // 6. h = x + ybf @ W_out
    gemm_bf16_kernel<3><<<dim3(DMODEL / 128, TOKENS / 128), blk, 0, stream>>>(
        ybf, WoutT, hbuf, nullptr, x, TOKENS, DMODEL, DIN);
    // 7. hnbf = bf16(rmsnorm(h))
    norm2_kernel<<<dim3(TOKENS), blk, 0, stream>>>(hbuf, hnbf, rms_w);
    // 8. midbf = bf16(silu(hnbf @ mlp_w1 + b1))
    gemm_bf16_kernel<1><<<dim3(MLP_INNER / 128, TOKENS / 128), blk, 0, stream>>>(
        hnbf, w1T, midbf, mlp_b1, nullptr, TOKENS, MLP_INNER, DMODEL);
    // 9. out = h + midbf @ mlp_w2 + b2
    gemm_bf16_kernel<2><<<dim3(DMODEL / 128, TOKENS / 128), blk, 0, stream>>>(
        midbf, w2T, out, mlp_b2, hbuf, TOKENS, DMODEL, MLP_INNER);
}

// Round 7
// 463.545 us; speedup vs baseline: 1.2672x; 1.0212x over previous
//
#include <hip/hip_runtime.h>
#include <hip/hip_bf16.h>
#include <cstdint>
#include <cstddef>

#define BATCH 2
#define SEQ 2048
#define DMODEL 1024
#define DIN 2048
#define NH 32
#define HEADDIM 64
#define DSTATE 64
#define DCONV 4
#define CONV_DIM (DIN + 2 * DSTATE)          // 2176
#define DPROJ (2 * DIN + 2 * DSTATE + NH)    // 4256
#define MLP_INNER 4096
#define TOKENS (BATCH * SEQ)                 // 4096
#define EPS 1e-5f
#define Q 64
#define NCHUNK (SEQ / Q)                     // 32
#define NCH (BATCH * NCHUNK * NH)            // 2048 chunk-heads
#define LSTR 72
#define NPAD_IN 4352                          // DPROJ padded to 34*128

typedef __attribute__((ext_vector_type(8))) short short8;
typedef __attribute__((ext_vector_type(8))) __bf16 bf16x8;
typedef __attribute__((ext_vector_type(4))) float f32x4;

__device__ inline short f2bf(float f) {
    unsigned u = __builtin_bit_cast(unsigned, f);
    u = (u + 0x7FFFu + ((u >> 16) & 1u)) >> 16;
    return (short)u;
}
__device__ inline float bf2f(short s) {
    unsigned u = ((unsigned)(unsigned short)s) << 16;
    return __builtin_bit_cast(float, u);
}
__device__ inline float silu_f(float x) { return x / (1.f + __expf(-x)); }

__device__ inline bf16x8 ld_frag(const short* p) {
    short8 s = *(const short8*)p;
    return __builtin_bit_cast(bf16x8, s);
}

__device__ inline void glds16(const short* g, short* l) {
    __builtin_amdgcn_global_load_lds(
        (const __attribute__((address_space(1))) void*)g,
        (__attribute__((address_space(3))) void*)l, 16, 0, 0);
}

// ---------------- bf16 GEMM, m97 structure + LDS dbuf + XCD swizzle ----------
// KT = K-tile per barrier (32 for high-block-count GEMMs, 64 for the 256-block
// N=1024 GEMMs: halves barrier count, doubles prefetch flight time at 1 blk/CU).
// MODE 0: f32 C = AB; 1: bf16 C = silu(AB+bias); 2: f32 C = AB+bias+res; 3: f32 C = AB+res
template <int MODE, int KT>
__global__ __launch_bounds__(256, 2) void gemm_bf16_kernel(
    const short* __restrict__ A, const short* __restrict__ BT,
    void* __restrict__ Cout, const float* __restrict__ bias,
    const float* __restrict__ res, int M, int N, int K)
{
    const int tid  = threadIdx.x;
    const int wid  = tid >> 6;
    const int lane = tid & 63;
    const int lm   = lane & 15;
    const int lg   = lane >> 4;

    const int nb  = gridDim.x * gridDim.y;
    const int bid = blockIdx.y * gridDim.x + blockIdx.x;
    const int per = nb >> 3;
    const int nid = (bid & 7) * per + (bid >> 3);
    const int m0  = (nid / gridDim.x) * 128;
    const int n0  = (nid % gridDim.x) * 128;

    __shared__ __attribute__((aligned(16))) short Al0[128 * KT];
    __shared__ __attribute__((aligned(16))) short Al1[128 * KT];
    __shared__ __attribute__((aligned(16))) short Bl0[128 * KT];
    __shared__ __attribute__((aligned(16))) short Bl1[128 * KT];

    f32x4 acc[4][4];
#pragma unroll
    for (int i = 0; i < 4; ++i)
#pragma unroll
        for (int j = 0; j < 4; ++j) acc[i][j] = {0.f, 0.f, 0.f, 0.f};

    const int wm = (wid >> 1) * 64;
    const int wn = (wid & 1) * 64;

    // staging geometry: each glds16 instr moves 64 lanes x 16B = 1 KiB
    const int lpr  = KT / 8;        // lanes per row (row = KT shorts = 2*KT B)
    const int rpi  = 64 / lpr;      // rows per glds16 instr
    const int nin  = 32 / rpi;      // glds16 instrs per matrix per wave (32 rows)
    const int srow = lane / lpr;
    const int scol = (lane % lpr) * 8;
    const short* Ag = A  + (size_t)(m0 + wid * 32 + srow) * K + scol;
    const short* Bg = BT + (size_t)(n0 + wid * 32 + srow) * K + scol;
    const int woff = wid * 32 * KT;  // wave's chunk in the LDS stage (shorts)

    const int niter = K / KT;
    // prologue: stage tile 0 into buf0
    {
#pragma unroll
        for (int j = 0; j < nin; ++j) {
            glds16(Ag + (size_t)j * rpi * K, Al0 + woff + j * 512);
            glds16(Bg + (size_t)j * rpi * K, Bl0 + woff + j * 512);
        }
    }

    for (int i = 0; i < niter; ++i) {
        __syncthreads();   // drains staging of buf[i&1]; protects overwrite
        const short* Ac = (i & 1) ? Al1 : Al0;
        const short* Bc = (i & 1) ? Bl1 : Bl0;
        if (i + 1 < niter) {
            int kt = (i + 1) * KT;
            short* al = ((i & 1) ? Al0 : Al1) + woff;
            short* bl = ((i & 1) ? Bl0 : Bl1) + woff;
#pragma unroll
            for (int j = 0; j < nin; ++j) {
                glds16(Ag + kt + (size_t)j * rpi * K, al + j * 512);
                glds16(Bg + kt + (size_t)j * rpi * K, bl + j * 512);
            }
        }

#pragma unroll
        for (int sub = 0; sub < KT / 32; ++sub) {
            bf16x8 af[4], bf[4];
#pragma unroll
            for (int ii = 0; ii < 4; ++ii)
                af[ii] = ld_frag(&Ac[(wm + ii * 16 + lm) * KT + sub * 32 + lg * 8]);
#pragma unroll
            for (int j = 0; j < 4; ++j)
                bf[j] = ld_frag(&Bc[(wn + j * 16 + lm) * KT + sub * 32 + lg * 8]);
#pragma unroll
            for (int ii = 0; ii < 4; ++ii)
#pragma unroll
                for (int j = 0; j < 4; ++j)
                    acc[ii][j] = __builtin_amdgcn_mfma_f32_16x16x32_bf16(af[ii], bf[j], acc[ii][j], 0, 0, 0);
        }
    }

#pragma unroll
    for (int i = 0; i < 4; ++i) {
#pragma unroll
        for (int j = 0; j < 4; ++j) {
            int col = n0 + wn + j * 16 + lm;
            if (col >= N) continue;
            float bv = (MODE == 1 || MODE == 2) ? bias[col] : 0.f;
#pragma unroll
            for (int r = 0; r < 4; ++r) {
                int row = m0 + wm + i * 16 + lg * 4 + r;
                float v = acc[i][j][r];
                if (MODE == 1) {
                    ((short*)Cout)[(size_t)row * N + col] = f2bf(silu_f(v + bv));
                } else {
                    if (MODE == 2) v = v + bv + res[(size_t)row * N + col];
                    if (MODE == 3) v = v + res[(size_t)row * N + col];
                    ((float*)Cout)[(size_t)row * N + col] = v;
                }
            }
        }
    }
}

// ---------------- f32 -> bf16 convert ----------------
__global__ __launch_bounds__(256) void cvt_kernel(
    const float* __restrict__ src, short* __restrict__ dst, int n4)
{
    int i = (blockIdx.x * 256 + threadIdx.x);
    if (i >= n4) return;
    f32x4 v = *(const f32x4*)(src + (size_t)i * 4);
    short4 o;
    o.x = f2bf(v.x); o.y = f2bf(v.y); o.z = f2bf(v.z); o.w = f2bf(v.w);
    *(short4*)(dst + (size_t)i * 4) = o;
}

// ---------------- W [K][N] f32 -> WT [Npad][K] bf16 ----------------
__global__ __launch_bounds__(256) void transpose_kernel(
    const float* __restrict__ src, short* __restrict__ dst, int K, int N)
{
    __shared__ float t[32][33];
    int bx = blockIdx.x, by = blockIdx.y;
    int col = threadIdx.x & 31, row8 = threadIdx.x >> 5;
    int gn = bx * 32 + col;
#pragma unroll
    for (int r = 0; r < 4; ++r) {
        int gk = by * 32 + row8 + r * 8;
        t[row8 + r * 8][col] = (gn < N) ? src[(size_t)gk * N + gn] : 0.f;
    }
    __syncthreads();
#pragma unroll
    for (int r = 0; r < 4; ++r) {
        int n = bx * 32 + row8 + r * 8;
        dst[(size_t)n * K + by * 32 + col] = f2bf(t[col][row8 + r * 8]);
    }
}

// ---------------- depthwise causal conv (k=4) + bias + silu, token-blocked ----
#define CTOK 8
__global__ __launch_bounds__(256) void conv_kernel(
    const float* __restrict__ zx, const float* __restrict__ cw,
    const float* __restrict__ cb, float* __restrict__ xBCc)
{
    int c4 = blockIdx.y * 256 + threadIdx.x;
    if (c4 >= CONV_DIM / 4) return;
    int c  = c4 * 4;
    int m0 = blockIdx.x * CTOK;
    int l0 = m0 & (SEQ - 1);

    const float* base = zx + (size_t)m0 * DPROJ + DIN + c;
    f32x4 win[CTOK + 3];
#pragma unroll
    for (int j = 0; j < CTOK + 3; ++j) {
        int off = j - 3;
        if (l0 + off >= 0)
            win[j] = *(const f32x4*)(base + (ptrdiff_t)off * DPROJ);
        else
            win[j] = {0.f, 0.f, 0.f, 0.f};
    }
    f32x4 w0 = *(const f32x4*)(cw + (c + 0) * DCONV);
    f32x4 w1 = *(const f32x4*)(cw + (c + 1) * DCONV);
    f32x4 w2 = *(const f32x4*)(cw + (c + 2) * DCONV);
    f32x4 w3 = *(const f32x4*)(cw + (c + 3) * DCONV);
    f32x4 bb = *(const f32x4*)(cb + c);

    float* outp = xBCc + (size_t)m0 * CONV_DIM + c;
#pragma unroll
    for (int t = 0; t < CTOK; ++t) {
        f32x4 a = {bb.x, bb.y, bb.z, bb.w};
#pragma unroll
        for (int j = 0; j < DCONV; ++j) {
            f32x4 v = win[t + j];
            a.x += v.x * w0[j];
            a.y += v.y * w1[j];
            a.z += v.z * w2[j];
            a.w += v.w * w3[j];
        }
        f32x4 o;
        o.x = silu_f(a.x); o.y = silu_f(a.y); o.z = silu_f(a.z); o.w = silu_f(a.w);
        *(f32x4*)(outp + (size_t)t * CONV_DIM) = o;
    }
}

// ---------------- dt = softplus(dt_raw + bias); ldA = A * dt ----------------
__global__ __launch_bounds__(256) void dt_kernel(
    const float* __restrict__ zx, const float* __restrict__ dt_bias,
    const float* __restrict__ A_log, float* __restrict__ dtb, float* __restrict__ ldab)
{
    int idx = blockIdx.x * 256 + threadIdx.x;
    if (idx >= TOKENS * NH) return;
    int hh = idx & (NH - 1);
    int m  = idx >> 5;
    float v  = zx[(size_t)m * DPROJ + DIN + CONV_DIM + hh] + dt_bias[hh];
    float dt = (v > 20.f) ? v : log1pf(__expf(v));
    dtb[idx]  = dt;
    ldab[idx] = -__expf(A_log[hh]) * dt;
}

// ---------------- P1: intra-chunk SSD ----------------
__global__ __launch_bounds__(256) void chunk_kernel(
    const float* __restrict__ xBCc, const float* __restrict__ dtb,
    const float* __restrict__ ldab, float* __restrict__ ybuf,
    float* __restrict__ Sbuf, float* __restrict__ cumdecay)
{
    int bid = blockIdx.x;
    int h = bid & 31, c = (bid >> 5) & 31, b = bid >> 10;
    int m0 = b * SEQ + c * Q;
    int tid = threadIdx.x;
    int wid = tid >> 6, lane = tid & 63, lm = lane & 15, lg = lane >> 4;

    __shared__ __attribute__((aligned(16))) short Cc[64 * LSTR];
    __shared__ __attribute__((aligned(16))) short Bb[64 * LSTR];
    __shared__ __attribute__((aligned(16))) short BwT[64 * LSTR];
    __shared__ __attribute__((aligned(16))) short Xt[64 * LSTR];
    __shared__ __attribute__((aligned(16))) short Mm[64 * LSTR];
    __shared__ float Lc[64], dtv[64];

    if (tid < 64) {
        int s = tid;
        size_t ix = (size_t)(m0 + s) * NH + h;
        float ld = ldab[ix];
        float dt = dtb[ix];
        float v = ld;
#pragma unroll
        for (int off = 1; off < 64; off <<= 1) {
            float o = __shfl_up(v, off);
            if (s >= off) v += o;
        }
        Lc[s] = v;
        dtv[s] = dt;
        cumdecay[(size_t)bid * 64 + s] = __expf(v);
    }
    {
        int row = tid >> 2, c0 = (tid & 3) * 16;
        const float* pB = xBCc + (size_t)(m0 + row) * CONV_DIM + DIN;
#pragma unroll
        for (int u = 0; u < 4; ++u) {
            f32x4 vb = *(const f32x4*)(pB + c0 + 4 * u);
            f32x4 vc = *(const f32x4*)(pB + DSTATE + c0 + 4 * u);
            short4 sb, sc;
            sb.x = f2bf(vb.x); sb.y = f2bf(vb.y); sb.z = f2bf(vb.z); sb.w = f2bf(vb.w);
            sc.x = f2bf(vc.x); sc.y = f2bf(vc.y); sc.z = f2bf(vc.z); sc.w = f2bf(vc.w);
            *(short4*)&Bb[row * LSTR + c0 + 4 * u] = sb;
            *(short4*)&Cc[row * LSTR + c0 + 4 * u] = sc;
        }
    }
    __syncthreads();
    {
        int s = tid >> 2, c0 = (tid & 3) * 16;
        float w = dtv[s];
        float w2 = __expf(Lc[63] - Lc[s]);
        const float* pX = xBCc + (size_t)(m0 + s) * CONV_DIM + h * HEADDIM;
#pragma unroll
        for (int u = 0; u < 4; ++u) {
            f32x4 v = *(const f32x4*)(pX + c0 + 4 * u);
            Xt[(c0 + 4 * u + 0) * LSTR + s] = f2bf(v.x * w);
            Xt[(c0 + 4 * u + 1) * LSTR + s] = f2bf(v.y * w);
            Xt[(c0 + 4 * u + 2) * LSTR + s] = f2bf(v.z * w);
            Xt[(c0 + 4 * u + 3) * LSTR + s] = f2bf(v.w * w);
            short4 sb = *(short4*)&Bb[s * LSTR + c0 + 4 * u];
            BwT[(c0 + 4 * u + 0) * LSTR + s] = f2bf(bf2f(sb.x) * w2);
            BwT[(c0 + 4 * u + 1) * LSTR + s] = f2bf(bf2f(sb.y) * w2);
            BwT[(c0 + 4 * u + 2) * LSTR + s] = f2bf(bf2f(sb.z) * w2);
            BwT[(c0 + 4 * u + 3) * LSTR + s] = f2bf(bf2f(sb.w) * w2);
        }
    }
    __syncthreads();

    {
        bf16x8 af[2];
#pragma unroll
        for (int kk = 0; kk < 2; ++kk)
            af[kk] = ld_frag(&Cc[(wid * 16 + lm) * LSTR + kk * 32 + lg * 8]);
#pragma unroll
        for (int j = 0; j < 4; ++j) {
            f32x4 acc = {0.f, 0.f, 0.f, 0.f};
#pragma unroll
            for (int kk = 0; kk < 2; ++kk) {
                bf16x8 bf = ld_frag(&Bb[(j * 16 + lm) * LSTR + kk * 32 + lg * 8]);
                acc = __builtin_amdgcn_mfma_f32_16x16x32_bf16(af[kk], bf, acc, 0, 0, 0);
            }
            int s = j * 16 + lm;
            float Ls = Lc[s];
#pragma unroll
            for (int r = 0; r < 4; ++r) {
                int t = wid * 16 + lg * 4 + r;
                float val = (s <= t) ? acc[r] * __expf(Lc[t] - Ls) : 0.f;
                Mm[t * LSTR + s] = f2bf(val);
            }
        }
    }
    __syncthreads();

    {
        bf16x8 am[2], aw[2];
#pragma unroll
        for (int kk = 0; kk < 2; ++kk) {
            am[kk] = ld_frag(&Mm[(wid * 16 + lm) * LSTR + kk * 32 + lg * 8]);
            aw[kk] = ld_frag(&BwT[(wid * 16 + lm) * LSTR + kk * 32 + lg * 8]);
        }
#pragma unroll
        for (int j = 0; j < 4; ++j) {
            f32x4 a1 = {0.f, 0.f, 0.f, 0.f};
            f32x4 a2 = {0.f, 0.f, 0.f, 0.f};
#pragma unroll
            for (int kk = 0; kk < 2; ++kk) {
                bf16x8 bx = ld_frag(&Xt[(j * 16 + lm) * LSTR + kk * 32 + lg * 8]);
                a1 = __builtin_amdgcn_mfma_f32_16x16x32_bf16(am[kk], bx, a1, 0, 0, 0);
                a2 = __builtin_amdgcn_mfma_f32_16x16x32_bf16(aw[kk], bx, a2, 0, 0, 0);
            }
            int p = j * 16 + lm;
#pragma unroll
            for (int r = 0; r < 4; ++r) {
                int t = wid * 16 + lg * 4 + r;
                ybuf[(size_t)(m0 + t) * DIN + h * HEADDIM + p] = a1[r];
                Sbuf[(size_t)bid * 4096 + t * 64 + p] = a2[r];
            }
        }
    }
}

// ---------------- P2: inter-chunk state recurrence ----------------
__global__ __launch_bounds__(256) void state_kernel(
    float* __restrict__ SH, const float* __restrict__ cumdecay)
{
    int bh = blockIdx.x;
    int b = bh >> 5, h = bh & 31;
    int tid = threadIdx.x;
    f32x4 H[4];
#pragma unroll
    for (int u = 0; u < 4; ++u) H[u] = {0.f, 0.f, 0.f, 0.f};
    for (int c = 0; c < NCHUNK; ++c) {
        int cid = (b * NCHUNK + c) * NH + h;
        size_t base = (size_t)cid * 4096 + (size_t)tid * 16;
        float cd = cumdecay[(size_t)cid * 64 + 63];
        f32x4 s[4];
#pragma unroll
        for (int u = 0; u < 4; ++u) s[u] = *(const f32x4*)(SH + base + u * 4);
#pragma unroll
        for (int u = 0; u < 4; ++u) *(f32x4*)(SH + base + u * 4) = H[u];
#pragma unroll
        for (int u = 0; u < 4; ++u) {
            H[u].x = cd * H[u].x + s[u].x;
            H[u].y = cd * H[u].y + s[u].y;
            H[u].z = cd * H[u].z + s[u].z;
            H[u].w = cd * H[u].w + s[u].w;
        }
    }
}

// ---------------- P3: y += exp(Lc_t) * C_t @ H_in ----------------
__global__ __launch_bounds__(256) void inter_kernel(
    const float* __restrict__ xBCc, const float* __restrict__ Hin,
    const float* __restrict__ cumdecay, float* __restrict__ ybuf)
{
    int bid = blockIdx.x;
    int h = bid & 31, c = (bid >> 5) & 31, b = bid >> 10;
    int m0 = b * SEQ + c * Q;
    int tid = threadIdx.x;
    int wid = tid >> 6, lane = tid & 63, lm = lane & 15, lg = lane >> 4;

    __shared__ __attribute__((aligned(16))) short Cc[64 * LSTR];
    __shared__ __attribute__((aligned(16))) short HT[64 * LSTR];
    __shared__ float eLc[64];

    if (tid < 64) eLc[tid] = cumdecay[(size_t)bid * 64 + tid];
    {
        int row = tid >> 2, c0 = (tid & 3) * 16;
        const float* pC = xBCc + (size_t)(m0 + row) * CONV_DIM + DIN + DSTATE;
        const float* pH = Hin + (size_t)bid * 4096 + row * 64;
#pragma unroll
        for (int u = 0; u < 4; ++u) {
            f32x4 vc = *(const f32x4*)(pC + c0 + 4 * u);
            short4 sc;
            sc.x = f2bf(vc.x); sc.y = f2bf(vc.y); sc.z = f2bf(vc.z); sc.w = f2bf(vc.w);
            *(short4*)&Cc[row * LSTR + c0 + 4 * u] = sc;
            f32x4 vh = *(const f32x4*)(pH + c0 + 4 * u);
            HT[(c0 + 4 * u + 0) * LSTR + row] = f2bf(vh.x);
            HT[(c0 + 4 * u + 1) * LSTR + row] = f2bf(vh.y);
            HT[(c0 + 4 * u + 2) * LSTR + row] = f2bf(vh.z);
            HT[(c0 + 4 * u + 3) * LSTR + row] = f2bf(vh.w);
        }
    }
    __syncthreads();

    bf16x8 af[2];
#pragma unroll
    for (int kk = 0; kk < 2; ++kk)
        af[kk] = ld_frag(&Cc[(wid * 16 + lm) * LSTR + kk * 32 + lg * 8]);
#pragma unroll
    for (int j = 0; j < 4; ++j) {
        f32x4 acc = {0.f, 0.f, 0.f, 0.f};
#pragma unroll
        for (int kk = 0; kk < 2; ++kk) {
            bf16x8 bh_ = ld_frag(&HT[(j * 16 + lm) * LSTR + kk * 32 + lg * 8]);
            acc = __builtin_amdgcn_mfma_f32_16x16x32_bf16(af[kk], bh_, acc, 0, 0, 0);
        }
        int p = j * 16 + lm;
#pragma unroll
        for (int r = 0; r < 4; ++r) {
            int t = wid * 16 + lg * 4 + r;
            size_t ya = (size_t)(m0 + t) * DIN + h * HEADDIM + p;
            ybuf[ya] += eLc[t] * acc[r];
        }
    }
}

// ---------------- ybf = bf16(rmsnorm((y + D*x) * silu(z), norm_w)) ----------------
__global__ __launch_bounds__(256) void norm1_kernel(
    const float* __restrict__ zx, const float* __restrict__ xBCc,
    const float* __restrict__ Dp, const float* __restrict__ y,
    short* __restrict__ ybf, const float* __restrict__ w)
{
    int m = blockIdx.x;
    int t = threadIdx.x;
    const float* zr = zx + (size_t)m * DPROJ;
    const float* xr = xBCc + (size_t)m * CONV_DIM;
    const float* yr = y + (size_t)m * DIN;
    float vals[8];
    float ss = 0.f;
#pragma unroll
    for (int j = 0; j < 8; ++j) {
        int i = j * 256 + t;
        float v = (yr[i] + Dp[i >> 6] * xr[i]) * silu_f(zr[i]);
        vals[j] = v;
        ss += v * v;
    }
#pragma unroll
    for (int o = 32; o >= 1; o >>= 1) ss += __shfl_xor(ss, o);
    __shared__ float wsum[4];
    if ((t & 63) == 0) wsum[t >> 6] = ss;
    __syncthreads();
    float tot = wsum[0] + wsum[1] + wsum[2] + wsum[3];
    float scale = rsqrtf(tot / (float)DIN + EPS);
#pragma unroll
    for (int j = 0; j < 8; ++j) {
        int i = j * 256 + t;
        ybf[(size_t)m * DIN + i] = f2bf(vals[j] * scale * w[i]);
    }
}

// ---------------- hnbf = bf16(rmsnorm(h, rms_w)) ----------------
__global__ __launch_bounds__(256) void norm2_kernel(
    const float* __restrict__ hb, short* __restrict__ hnbf, const float* __restrict__ w)
{
    int m = blockIdx.x;
    int t = threadIdx.x;
    const float* hr = hb + (size_t)m * DMODEL;
    float vals[4];
    float ss = 0.f;
#pragma unroll
    for (int j = 0; j < 4; ++j) {
        int i = j * 256 + t;
        float v = hr[i];
        vals[j] = v;
        ss += v * v;
    }
#pragma unroll
    for (int o = 32; o >= 1; o >>= 1) ss += __shfl_xor(ss, o);
    __shared__ float wsum[4];
    if ((t & 63) == 0) wsum[t >> 6] = ss;
    __syncthreads();
    float tot = wsum[0] + wsum[1] + wsum[2] + wsum[3];
    float scale = rsqrtf(tot / (float)DMODEL + EPS);
#pragma unroll
    for (int j = 0; j < 4; ++j) {
        int i = j * 256 + t;
        hnbf[(size_t)m * DMODEL + i] = f2bf(vals[j] * scale * w[i]);
    }
}

extern "C" void kernel_launch(void* const* d_in, const int* in_sizes, int n_in,
                              void* d_out, int out_size, void* d_ws, size_t ws_size,
                              hipStream_t stream) {
    const float* x       = (const float*)d_in[0];
    const float* W_in    = (const float*)d_in[1];
    const float* conv_w  = (const float*)d_in[2];
    const float* conv_b  = (const float*)d_in[3];
    const float* dt_bias = (const float*)d_in[4];
    const float* A_log   = (const float*)d_in[5];
    const float* D_param = (const float*)d_in[6];
    const float* norm_w  = (const float*)d_in[7];
    const float* W_out   = (const float*)d_in[8];
    const float* rms_w   = (const float*)d_in[9];
    const float* mlp_w1  = (const float*)d_in[10];
    const float* mlp_b1  = (const float*)d_in[11];
    const float* mlp_w2  = (const float*)d_in[12];
    const float* mlp_b2  = (const float*)d_in[13];
    float* out = (float*)d_out;

    float* ws       = (float*)d_ws;
    float* zx       = ws;
    float* xBCc     = zx + (size_t)TOKENS * DPROJ;
    float* dtb      = xBCc + (size_t)TOKENS * CONV_DIM;
    float* ldab     = dtb + (size_t)TOKENS * NH;
    float* cumdecay = ldab + (size_t)TOKENS * NH;
    float* ybuf     = cumdecay + (size_t)TOKENS * NH;
    float* SH       = ybuf + (size_t)TOKENS * DIN;
    float* bfarea   = SH + (size_t)NCH * 4096;

    short* xbf   = (short*)ybuf;
    short* midbf = (short*)ybuf;
    float* hbuf  = SH;
    short* hnbf  = (short*)(SH + (size_t)TOKENS * DMODEL);

    short* ybf   = (short*)bfarea;
    short* WinT  = ybf + (size_t)TOKENS * DIN;
    short* WoutT = WinT + (size_t)NPAD_IN * DMODEL;
    short* w1T   = WoutT + (size_t)DMODEL * DIN;
    short* w2T   = w1T + (size_t)MLP_INNER * DMODEL;

    dim3 blk(256);

    // 0. conversions / weight transposes
    cvt_kernel<<<dim3(TOKENS * DMODEL / 4 / 256), blk, 0, stream>>>(x, xbf, TOKENS * DMODEL / 4);
    transpose_kernel<<<dim3(NPAD_IN / 32, DMODEL / 32), blk, 0, stream>>>(W_in, WinT, DMODEL, DPROJ);
    transpose_kernel<<<dim3(DMODEL / 32, DIN / 32), blk, 0, stream>>>(W_out, WoutT, DIN, DMODEL);
    transpose_kernel<<<dim3(MLP_INNER / 32, DMODEL / 32), blk, 0, stream>>>(mlp_w1, w1T, DMODEL, MLP_INNER);
    transpose_kernel<<<dim3(DMODEL / 32, MLP_INNER / 32), blk, 0, stream>>>(mlp_w2, w2T, MLP_INNER, DMODEL);

    // 1. zx = x @ W_in  (1088 blocks, 4/CU -> KT=32)
    gemm_bf16_kernel<0, 32><<<dim3(NPAD_IN / 128, TOKENS / 128), blk, 0, stream>>>(
        xbf, WinT, zx, nullptr, nullptr, TOKENS, DPROJ, DMODEL);
    // 2. conv + bias + silu (token-blocked)
    conv_kernel<<<dim3(TOKENS / CTOK, (CONV_DIM / 4 + 255) / 256), blk, 0, stream>>>(
        zx, conv_w, conv_b, xBCc);
    // 3. dt / ldA
    dt_kernel<<<dim3(TOKENS * NH / 256), blk, 0, stream>>>(zx, dt_bias, A_log, dtb, ldab);
    // 4. SSD
    chunk_kernel<<<dim3(NCH), blk, 0, stream>>>(xBCc, dtb, ldab, ybuf, SH, cumdecay);
    state_kernel<<<dim3(BATCH * NH), blk, 0, stream>>>(SH, cumdecay);
    inter_kernel<<<dim3(NCH), blk, 0, stream>>>(xBCc, SH, cumdecay, ybuf);
    // 5. ybf = bf16(rmsnorm((y + D*x) * silu(z)))
    norm1_kernel<<<dim3(TOKENS), blk, 0, stream>>>(zx, xBCc, D_param, ybuf, ybf, norm_w);
    // 6. h = x + ybf @ W_out  (256 blocks, 1/CU -> KT=64)
    gemm_bf16_kernel<3, 64><<<dim3(DMODEL / 128, TOKENS / 128), blk, 0, stream>>>(
        ybf, WoutT, hbuf, nullptr, x, TOKENS, DMODEL, DIN);
    // 7. hnbf = bf16(rmsnorm(h))
    norm2_kernel<<<dim3(TOKENS), blk, 0, stream>>>(hbuf, hnbf, rms_w);
    // 8. midbf = bf16(silu(hnbf @ mlp_w1 + b1))  (1024 blocks, 4/CU -> KT=32)
    gemm_bf16_kernel<1, 32><<<dim3(MLP_INNER / 128, TOKENS / 128), blk, 0, stream>>>(
        hnbf, w1T, midbf, mlp_b1, nullptr, TOKENS, MLP_INNER, DMODEL);
    // 9. out = h + midbf @ mlp_w2 + b2  (256 blocks, 1/CU -> KT=64)
    gemm_bf16_kernel<2, 64><<<dim3(DMODEL / 128, TOKENS / 128), blk, 0, stream>>>(
        midbf, w2T, out, mlp_b2, hbuf, TOKENS, DMODEL, MLP_INNER);
}

// Round 8
// 444.829 us; speedup vs baseline: 1.3205x; 1.0421x over previous
//
#include <hip/hip_runtime.h>
#include <hip/hip_bf16.h>
#include <cstdint>
#include <cstddef>

#define BATCH 2
#define SEQ 2048
#define DMODEL 1024
#define DIN 2048
#define NH 32
#define HEADDIM 64
#define DSTATE 64
#define DCONV 4
#define CONV_DIM (DIN + 2 * DSTATE)          // 2176
#define DPROJ (2 * DIN + 2 * DSTATE + NH)    // 4256
#define MLP_INNER 4096
#define TOKENS (BATCH * SEQ)                 // 4096
#define EPS 1e-5f
#define Q 64
#define NCHUNK (SEQ / Q)                     // 32
#define NCH (BATCH * NCHUNK * NH)            // 2048 chunk-heads
#define LSTR 72
#define NPAD_IN 4352                          // DPROJ padded to 34*128

typedef __attribute__((ext_vector_type(8))) short short8;
typedef __attribute__((ext_vector_type(8))) __bf16 bf16x8;
typedef __attribute__((ext_vector_type(4))) float f32x4;

__device__ inline short f2bf(float f) {
    unsigned u = __builtin_bit_cast(unsigned, f);
    u = (u + 0x7FFFu + ((u >> 16) & 1u)) >> 16;
    return (short)u;
}
__device__ inline float bf2f(short s) {
    unsigned u = ((unsigned)(unsigned short)s) << 16;
    return __builtin_bit_cast(float, u);
}
__device__ inline float silu_f(float x) { return x / (1.f + __expf(-x)); }

__device__ inline bf16x8 ld_frag(const short* p) {
    short8 s = *(const short8*)p;
    return __builtin_bit_cast(bf16x8, s);
}

__device__ inline void glds16(const short* g, short* l) {
    __builtin_amdgcn_global_load_lds(
        (const __attribute__((address_space(1))) void*)g,
        (__attribute__((address_space(3))) void*)l, 16, 0, 0);
}

// ---------------- bf16 GEMM: m97 staging + LDS dbuf + XCD swizzle + XOR-swizzled LDS ----
// LDS layout: 16B block `cb` of row r stored at physical slot (cb ^ (r & (lpr-1))).
// Staging picks the swizzled global block per lane (LDS dest is fixed lane*16B);
// reads apply the same XOR. KT=64 -> 2-way (free); KT=32 -> 4-way (was 8-way).
// MODE 0: f32 C = AB; 1: bf16 C = silu(AB+bias); 2: f32 C = AB+bias+res; 3: f32 C = AB+res
template <int MODE, int KT>
__global__ __launch_bounds__(256, 2) void gemm_bf16_kernel(
    const short* __restrict__ A, const short* __restrict__ BT,
    void* __restrict__ Cout, const float* __restrict__ bias,
    const float* __restrict__ res, int M, int N, int K)
{
    const int tid  = threadIdx.x;
    const int wid  = tid >> 6;
    const int lane = tid & 63;
    const int lm   = lane & 15;
    const int lg   = lane >> 4;

    const int nb  = gridDim.x * gridDim.y;
    const int bid = blockIdx.y * gridDim.x + blockIdx.x;
    const int per = nb >> 3;
    const int nid = (bid & 7) * per + (bid >> 3);
    const int m0  = (nid / gridDim.x) * 128;
    const int n0  = (nid % gridDim.x) * 128;

    __shared__ __attribute__((aligned(16))) short Al0[128 * KT];
    __shared__ __attribute__((aligned(16))) short Al1[128 * KT];
    __shared__ __attribute__((aligned(16))) short Bl0[128 * KT];
    __shared__ __attribute__((aligned(16))) short Bl1[128 * KT];

    f32x4 acc[4][4];
#pragma unroll
    for (int i = 0; i < 4; ++i)
#pragma unroll
        for (int j = 0; j < 4; ++j) acc[i][j] = {0.f, 0.f, 0.f, 0.f};

    const int wm = (wid >> 1) * 64;
    const int wn = (wid & 1) * 64;

    // staging geometry: each glds16 moves 64 lanes x 16B = 1 KiB
    constexpr int lpr = KT / 8;      // 16B blocks per row
    constexpr int rpi = 64 / lpr;    // rows per glds16 instr
    constexpr int nin = 32 / rpi;    // glds16 instrs per matrix per wave
    const int srow = lane / lpr;
    const int scb  = (lane % lpr) ^ (srow & (lpr - 1));   // swizzled source block
    const int scol = scb * 8;
    // row bases (wid*32, j*rpi) are multiples of lpr, so (row & (lpr-1)) == (srow & (lpr-1))
    const short* Ag = A  + (size_t)(m0 + wid * 32 + srow) * K + scol;
    const short* Bg = BT + (size_t)(n0 + wid * 32 + srow) * K + scol;
    const int woff = wid * 32 * KT;

    const int niter = K / KT;
    {
#pragma unroll
        for (int j = 0; j < nin; ++j) {
            glds16(Ag + (size_t)j * rpi * K, Al0 + woff + j * 512);
            glds16(Bg + (size_t)j * rpi * K, Bl0 + woff + j * 512);
        }
    }

    for (int i = 0; i < niter; ++i) {
        __syncthreads();
        const short* Ac = (i & 1) ? Al1 : Al0;
        const short* Bc = (i & 1) ? Bl1 : Bl0;
        if (i + 1 < niter) {
            int kt = (i + 1) * KT;
            short* al = ((i & 1) ? Al0 : Al1) + woff;
            short* bl = ((i & 1) ? Bl0 : Bl1) + woff;
#pragma unroll
            for (int j = 0; j < nin; ++j) {
                glds16(Ag + kt + (size_t)j * rpi * K, al + j * 512);
                glds16(Bg + kt + (size_t)j * rpi * K, bl + j * 512);
            }
        }

#pragma unroll
        for (int sub = 0; sub < KT / 32; ++sub) {
            const int cb = sub * 4 + lg;           // logical 16B block index
            bf16x8 af[4], bf[4];
#pragma unroll
            for (int ii = 0; ii < 4; ++ii) {
                int ar = wm + ii * 16 + lm;
                af[ii] = ld_frag(&Ac[ar * KT + ((cb ^ (ar & (lpr - 1))) * 8)]);
            }
#pragma unroll
            for (int j = 0; j < 4; ++j) {
                int br = wn + j * 16 + lm;
                bf[j] = ld_frag(&Bc[br * KT + ((cb ^ (br & (lpr - 1))) * 8)]);
            }
#pragma unroll
            for (int ii = 0; ii < 4; ++ii)
#pragma unroll
                for (int j = 0; j < 4; ++j)
                    acc[ii][j] = __builtin_amdgcn_mfma_f32_16x16x32_bf16(af[ii], bf[j], acc[ii][j], 0, 0, 0);
        }
    }

#pragma unroll
    for (int i = 0; i < 4; ++i) {
#pragma unroll
        for (int j = 0; j < 4; ++j) {
            int col = n0 + wn + j * 16 + lm;
            if (col >= N) continue;
            float bv = (MODE == 1 || MODE == 2) ? bias[col] : 0.f;
#pragma unroll
            for (int r = 0; r < 4; ++r) {
                int row = m0 + wm + i * 16 + lg * 4 + r;
                float v = acc[i][j][r];
                if (MODE == 1) {
                    ((short*)Cout)[(size_t)row * N + col] = f2bf(silu_f(v + bv));
                } else {
                    if (MODE == 2) v = v + bv + res[(size_t)row * N + col];
                    if (MODE == 3) v = v + res[(size_t)row * N + col];
                    ((float*)Cout)[(size_t)row * N + col] = v;
                }
            }
        }
    }
}

// ---------------- f32 -> bf16 convert ----------------
__global__ __launch_bounds__(256) void cvt_kernel(
    const float* __restrict__ src, short* __restrict__ dst, int n4)
{
    int i = (blockIdx.x * 256 + threadIdx.x);
    if (i >= n4) return;
    f32x4 v = *(const f32x4*)(src + (size_t)i * 4);
    short4 o;
    o.x = f2bf(v.x); o.y = f2bf(v.y); o.z = f2bf(v.z); o.w = f2bf(v.w);
    *(short4*)(dst + (size_t)i * 4) = o;
}

// ---------------- W [K][N] f32 -> WT [Npad][K] bf16 ----------------
__global__ __launch_bounds__(256) void transpose_kernel(
    const float* __restrict__ src, short* __restrict__ dst, int K, int N)
{
    __shared__ float t[32][33];
    int bx = blockIdx.x, by = blockIdx.y;
    int col = threadIdx.x & 31, row8 = threadIdx.x >> 5;
    int gn = bx * 32 + col;
#pragma unroll
    for (int r = 0; r < 4; ++r) {
        int gk = by * 32 + row8 + r * 8;
        t[row8 + r * 8][col] = (gn < N) ? src[(size_t)gk * N + gn] : 0.f;
    }
    __syncthreads();
#pragma unroll
    for (int r = 0; r < 4; ++r) {
        int n = bx * 32 + row8 + r * 8;
        dst[(size_t)n * K + by * 32 + col] = f2bf(t[col][row8 + r * 8]);
    }
}

// ---------------- depthwise causal conv (k=4) + bias + silu, token-blocked ----
#define CTOK 8
__global__ __launch_bounds__(256) void conv_kernel(
    const float* __restrict__ zx, const float* __restrict__ cw,
    const float* __restrict__ cb, float* __restrict__ xBCc)
{
    int c4 = blockIdx.y * 256 + threadIdx.x;
    if (c4 >= CONV_DIM / 4) return;
    int c  = c4 * 4;
    int m0 = blockIdx.x * CTOK;
    int l0 = m0 & (SEQ - 1);

    const float* base = zx + (size_t)m0 * DPROJ + DIN + c;
    f32x4 win[CTOK + 3];
#pragma unroll
    for (int j = 0; j < CTOK + 3; ++j) {
        int off = j - 3;
        if (l0 + off >= 0)
            win[j] = *(const f32x4*)(base + (ptrdiff_t)off * DPROJ);
        else
            win[j] = {0.f, 0.f, 0.f, 0.f};
    }
    f32x4 w0 = *(const f32x4*)(cw + (c + 0) * DCONV);
    f32x4 w1 = *(const f32x4*)(cw + (c + 1) * DCONV);
    f32x4 w2 = *(const f32x4*)(cw + (c + 2) * DCONV);
    f32x4 w3 = *(const f32x4*)(cw + (c + 3) * DCONV);
    f32x4 bb = *(const f32x4*)(cb + c);

    float* outp = xBCc + (size_t)m0 * CONV_DIM + c;
#pragma unroll
    for (int t = 0; t < CTOK; ++t) {
        f32x4 a = {bb.x, bb.y, bb.z, bb.w};
#pragma unroll
        for (int j = 0; j < DCONV; ++j) {
            f32x4 v = win[t + j];
            a.x += v.x * w0[j];
            a.y += v.y * w1[j];
            a.z += v.z * w2[j];
            a.w += v.w * w3[j];
        }
        f32x4 o;
        o.x = silu_f(a.x); o.y = silu_f(a.y); o.z = silu_f(a.z); o.w = silu_f(a.w);
        *(f32x4*)(outp + (size_t)t * CONV_DIM) = o;
    }
}

// ---------------- dt = softplus(dt_raw + bias); ldA = A * dt ----------------
__global__ __launch_bounds__(256) void dt_kernel(
    const float* __restrict__ zx, const float* __restrict__ dt_bias,
    const float* __restrict__ A_log, float* __restrict__ dtb, float* __restrict__ ldab)
{
    int idx = blockIdx.x * 256 + threadIdx.x;
    if (idx >= TOKENS * NH) return;
    int hh = idx & (NH - 1);
    int m  = idx >> 5;
    float v  = zx[(size_t)m * DPROJ + DIN + CONV_DIM + hh] + dt_bias[hh];
    float dt = (v > 20.f) ? v : log1pf(__expf(v));
    dtb[idx]  = dt;
    ldab[idx] = -__expf(A_log[hh]) * dt;
}

// ---------------- P1: intra-chunk SSD ----------------
__global__ __launch_bounds__(256) void chunk_kernel(
    const float* __restrict__ xBCc, const float* __restrict__ dtb,
    const float* __restrict__ ldab, float* __restrict__ ybuf,
    float* __restrict__ Sbuf, float* __restrict__ cumdecay)
{
    int bid = blockIdx.x;
    int h = bid & 31, c = (bid >> 5) & 31, b = bid >> 10;
    int m0 = b * SEQ + c * Q;
    int tid = threadIdx.x;
    int wid = tid >> 6, lane = tid & 63, lm = lane & 15, lg = lane >> 4;

    __shared__ __attribute__((aligned(16))) short Cc[64 * LSTR];
    __shared__ __attribute__((aligned(16))) short Bb[64 * LSTR];
    __shared__ __attribute__((aligned(16))) short BwT[64 * LSTR];
    __shared__ __attribute__((aligned(16))) short Xt[64 * LSTR];
    __shared__ __attribute__((aligned(16))) short Mm[64 * LSTR];
    __shared__ float Lc[64], dtv[64];

    if (tid < 64) {
        int s = tid;
        size_t ix = (size_t)(m0 + s) * NH + h;
        float ld = ldab[ix];
        float dt = dtb[ix];
        float v = ld;
#pragma unroll
        for (int off = 1; off < 64; off <<= 1) {
            float o = __shfl_up(v, off);
            if (s >= off) v += o;
        }
        Lc[s] = v;
        dtv[s] = dt;
        cumdecay[(size_t)bid * 64 + s] = __expf(v);
    }
    {
        int row = tid >> 2, c0 = (tid & 3) * 16;
        const float* pB = xBCc + (size_t)(m0 + row) * CONV_DIM + DIN;
#pragma unroll
        for (int u = 0; u < 4; ++u) {
            f32x4 vb = *(const f32x4*)(pB + c0 + 4 * u);
            f32x4 vc = *(const f32x4*)(pB + DSTATE + c0 + 4 * u);
            short4 sb, sc;
            sb.x = f2bf(vb.x); sb.y = f2bf(vb.y); sb.z = f2bf(vb.z); sb.w = f2bf(vb.w);
            sc.x = f2bf(vc.x); sc.y = f2bf(vc.y); sc.z = f2bf(vc.z); sc.w = f2bf(vc.w);
            *(short4*)&Bb[row * LSTR + c0 + 4 * u] = sb;
            *(short4*)&Cc[row * LSTR + c0 + 4 * u] = sc;
        }
    }
    __syncthreads();
    {
        int s = tid >> 2, c0 = (tid & 3) * 16;
        float w = dtv[s];
        float w2 = __expf(Lc[63] - Lc[s]);
        const float* pX = xBCc + (size_t)(m0 + s) * CONV_DIM + h * HEADDIM;
#pragma unroll
        for (int u = 0; u < 4; ++u) {
            f32x4 v = *(const f32x4*)(pX + c0 + 4 * u);
            Xt[(c0 + 4 * u + 0) * LSTR + s] = f2bf(v.x * w);
            Xt[(c0 + 4 * u + 1) * LSTR + s] = f2bf(v.y * w);
            Xt[(c0 + 4 * u + 2) * LSTR + s] = f2bf(v.z * w);
            Xt[(c0 + 4 * u + 3) * LSTR + s] = f2bf(v.w * w);
            short4 sb = *(short4*)&Bb[s * LSTR + c0 + 4 * u];
            BwT[(c0 + 4 * u + 0) * LSTR + s] = f2bf(bf2f(sb.x) * w2);
            BwT[(c0 + 4 * u + 1) * LSTR + s] = f2bf(bf2f(sb.y) * w2);
            BwT[(c0 + 4 * u + 2) * LSTR + s] = f2bf(bf2f(sb.z) * w2);
            BwT[(c0 + 4 * u + 3) * LSTR + s] = f2bf(bf2f(sb.w) * w2);
        }
    }
    __syncthreads();

    {
        bf16x8 af[2];
#pragma unroll
        for (int kk = 0; kk < 2; ++kk)
            af[kk] = ld_frag(&Cc[(wid * 16 + lm) * LSTR + kk * 32 + lg * 8]);
#pragma unroll
        for (int j = 0; j < 4; ++j) {
            f32x4 acc = {0.f, 0.f, 0.f, 0.f};
#pragma unroll
            for (int kk = 0; kk < 2; ++kk) {
                bf16x8 bf = ld_frag(&Bb[(j * 16 + lm) * LSTR + kk * 32 + lg * 8]);
                acc = __builtin_amdgcn_mfma_f32_16x16x32_bf16(af[kk], bf, acc, 0, 0, 0);
            }
            int s = j * 16 + lm;
            float Ls = Lc[s];
#pragma unroll
            for (int r = 0; r < 4; ++r) {
                int t = wid * 16 + lg * 4 + r;
                float val = (s <= t) ? acc[r] * __expf(Lc[t] - Ls) : 0.f;
                Mm[t * LSTR + s] = f2bf(val);
            }
        }
    }
    __syncthreads();

    {
        bf16x8 am[2], aw[2];
#pragma unroll
        for (int kk = 0; kk < 2; ++kk) {
            am[kk] = ld_frag(&Mm[(wid * 16 + lm) * LSTR + kk * 32 + lg * 8]);
            aw[kk] = ld_frag(&BwT[(wid * 16 + lm) * LSTR + kk * 32 + lg * 8]);
        }
#pragma unroll
        for (int j = 0; j < 4; ++j) {
            f32x4 a1 = {0.f, 0.f, 0.f, 0.f};
            f32x4 a2 = {0.f, 0.f, 0.f, 0.f};
#pragma unroll
            for (int kk = 0; kk < 2; ++kk) {
                bf16x8 bx = ld_frag(&Xt[(j * 16 + lm) * LSTR + kk * 32 + lg * 8]);
                a1 = __builtin_amdgcn_mfma_f32_16x16x32_bf16(am[kk], bx, a1, 0, 0, 0);
                a2 = __builtin_amdgcn_mfma_f32_16x16x32_bf16(aw[kk], bx, a2, 0, 0, 0);
            }
            int p = j * 16 + lm;
#pragma unroll
            for (int r = 0; r < 4; ++r) {
                int t = wid * 16 + lg * 4 + r;
                ybuf[(size_t)(m0 + t) * DIN + h * HEADDIM + p] = a1[r];
                Sbuf[(size_t)bid * 4096 + t * 64 + p] = a2[r];
            }
        }
    }
}

// ---------------- P2: inter-chunk state recurrence ----------------
__global__ __launch_bounds__(256) void state_kernel(
    float* __restrict__ SH, const float* __restrict__ cumdecay)
{
    int bh = blockIdx.x;
    int b = bh >> 5, h = bh & 31;
    int tid = threadIdx.x;
    f32x4 H[4];
#pragma unroll
    for (int u = 0; u < 4; ++u) H[u] = {0.f, 0.f, 0.f, 0.f};
    for (int c = 0; c < NCHUNK; ++c) {
        int cid = (b * NCHUNK + c) * NH + h;
        size_t base = (size_t)cid * 4096 + (size_t)tid * 16;
        float cd = cumdecay[(size_t)cid * 64 + 63];
        f32x4 s[4];
#pragma unroll
        for (int u = 0; u < 4; ++u) s[u] = *(const f32x4*)(SH + base + u * 4);
#pragma unroll
        for (int u = 0; u < 4; ++u) *(f32x4*)(SH + base + u * 4) = H[u];
#pragma unroll
        for (int u = 0; u < 4; ++u) {
            H[u].x = cd * H[u].x + s[u].x;
            H[u].y = cd * H[u].y + s[u].y;
            H[u].z = cd * H[u].z + s[u].z;
            H[u].w = cd * H[u].w + s[u].w;
        }
    }
}

// ---------------- P3: y += exp(Lc_t) * C_t @ H_in ----------------
__global__ __launch_bounds__(256) void inter_kernel(
    const float* __restrict__ xBCc, const float* __restrict__ Hin,
    const float* __restrict__ cumdecay, float* __restrict__ ybuf)
{
    int bid = blockIdx.x;
    int h = bid & 31, c = (bid >> 5) & 31, b = bid >> 10;
    int m0 = b * SEQ + c * Q;
    int tid = threadIdx.x;
    int wid = tid >> 6, lane = tid & 63, lm = lane & 15, lg = lane >> 4;

    __shared__ __attribute__((aligned(16))) short Cc[64 * LSTR];
    __shared__ __attribute__((aligned(16))) short HT[64 * LSTR];
    __shared__ float eLc[64];

    if (tid < 64) eLc[tid] = cumdecay[(size_t)bid * 64 + tid];
    {
        int row = tid >> 2, c0 = (tid & 3) * 16;
        const float* pC = xBCc + (size_t)(m0 + row) * CONV_DIM + DIN + DSTATE;
        const float* pH = Hin + (size_t)bid * 4096 + row * 64;
#pragma unroll
        for (int u = 0; u < 4; ++u) {
            f32x4 vc = *(const f32x4*)(pC + c0 + 4 * u);
            short4 sc;
            sc.x = f2bf(vc.x); sc.y = f2bf(vc.y); sc.z = f2bf(vc.z); sc.w = f2bf(vc.w);
            *(short4*)&Cc[row * LSTR + c0 + 4 * u] = sc;
            f32x4 vh = *(const f32x4*)(pH + c0 + 4 * u);
            HT[(c0 + 4 * u + 0) * LSTR + row] = f2bf(vh.x);
            HT[(c0 + 4 * u + 1) * LSTR + row] = f2bf(vh.y);
            HT[(c0 + 4 * u + 2) * LSTR + row] = f2bf(vh.z);
            HT[(c0 + 4 * u + 3) * LSTR + row] = f2bf(vh.w);
        }
    }
    __syncthreads();

    bf16x8 af[2];
#pragma unroll
    for (int kk = 0; kk < 2; ++kk)
        af[kk] = ld_frag(&Cc[(wid * 16 + lm) * LSTR + kk * 32 + lg * 8]);
#pragma unroll
    for (int j = 0; j < 4; ++j) {
        f32x4 acc = {0.f, 0.f, 0.f, 0.f};
#pragma unroll
        for (int kk = 0; kk < 2; ++kk) {
            bf16x8 bh_ = ld_frag(&HT[(j * 16 + lm) * LSTR + kk * 32 + lg * 8]);
            acc = __builtin_amdgcn_mfma_f32_16x16x32_bf16(af[kk], bh_, acc, 0, 0, 0);
        }
        int p = j * 16 + lm;
#pragma unroll
        for (int r = 0; r < 4; ++r) {
            int t = wid * 16 + lg * 4 + r;
            size_t ya = (size_t)(m0 + t) * DIN + h * HEADDIM + p;
            ybuf[ya] += eLc[t] * acc[r];
        }
    }
}

// ---------------- ybf = bf16(rmsnorm((y + D*x) * silu(z), norm_w)) ----------------
__global__ __launch_bounds__(256) void norm1_kernel(
    const float* __restrict__ zx, const float* __restrict__ xBCc,
    const float* __restrict__ Dp, const float* __restrict__ y,
    short* __restrict__ ybf, const float* __restrict__ w)
{
    int m = blockIdx.x;
    int t = threadIdx.x;
    const float* zr = zx + (size_t)m * DPROJ;
    const float* xr = xBCc + (size_t)m * CONV_DIM;
    const float* yr = y + (size_t)m * DIN;
    float vals[8];
    float ss = 0.f;
#pragma unroll
    for (int j = 0; j < 8; ++j) {
        int i = j * 256 + t;
        float v = (yr[i] + Dp[i >> 6] * xr[i]) * silu_f(zr[i]);
        vals[j] = v;
        ss += v * v;
    }
#pragma unroll
    for (int o = 32; o >= 1; o >>= 1) ss += __shfl_xor(ss, o);
    __shared__ float wsum[4];
    if ((t & 63) == 0) wsum[t >> 6] = ss;
    __syncthreads();
    float tot = wsum[0] + wsum[1] + wsum[2] + wsum[3];
    float scale = rsqrtf(tot / (float)DIN + EPS);
#pragma unroll
    for (int j = 0; j < 8; ++j) {
        int i = j * 256 + t;
        ybf[(size_t)m * DIN + i] = f2bf(vals[j] * scale * w[i]);
    }
}

// ---------------- hnbf = bf16(rmsnorm(h, rms_w)) ----------------
__global__ __launch_bounds__(256) void norm2_kernel(
    const float* __restrict__ hb, short* __restrict__ hnbf, const float* __restrict__ w)
{
    int m = blockIdx.x;
    int t = threadIdx.x;
    const float* hr = hb + (size_t)m * DMODEL;
    float vals[4];
    float ss = 0.f;
#pragma unroll
    for (int j = 0; j < 4; ++j) {
        int i = j * 256 + t;
        float v = hr[i];
        vals[j] = v;
        ss += v * v;
    }
#pragma unroll
    for (int o = 32; o >= 1; o >>= 1) ss += __shfl_xor(ss, o);
    __shared__ float wsum[4];
    if ((t & 63) == 0) wsum[t >> 6] = ss;
    __syncthreads();
    float tot = wsum[0] + wsum[1] + wsum[2] + wsum[3];
    float scale = rsqrtf(tot / (float)DMODEL + EPS);
#pragma unroll
    for (int j = 0; j < 4; ++j) {
        int i = j * 256 + t;
        hnbf[(size_t)m * DMODEL + i] = f2bf(vals[j] * scale * w[i]);
    }
}

extern "C" void kernel_launch(void* const* d_in, const int* in_sizes, int n_in,
                              void* d_out, int out_size, void* d_ws, size_t ws_size,
                              hipStream_t stream) {
    const float* x       = (const float*)d_in[0];
    const float* W_in    = (const float*)d_in[1];
    const float* conv_w  = (const float*)d_in[2];
    const float* conv_b  = (const float*)d_in[3];
    const float* dt_bias = (const float*)d_in[4];
    const float* A_log   = (const float*)d_in[5];
    const float* D_param = (const float*)d_in[6];
    const float* norm_w  = (const float*)d_in[7];
    const float* W_out   = (const float*)d_in[8];
    const float* rms_w   = (const float*)d_in[9];
    const float* mlp_w1  = (const float*)d_in[10];
    const float* mlp_b1  = (const float*)d_in[11];
    const float* mlp_w2  = (const float*)d_in[12];
    const float* mlp_b2  = (const float*)d_in[13];
    float* out = (float*)d_out;

    float* ws       = (float*)d_ws;
    float* zx       = ws;
    float* xBCc     = zx + (size_t)TOKENS * DPROJ;
    float* dtb      = xBCc + (size_t)TOKENS * CONV_DIM;
    float* ldab     = dtb + (size_t)TOKENS * NH;
    float* cumdecay = ldab + (size_t)TOKENS * NH;
    float* ybuf     = cumdecay + (size_t)TOKENS * NH;
    float* SH       = ybuf + (size_t)TOKENS * DIN;
    float* bfarea   = SH + (size_t)NCH * 4096;

    short* xbf   = (short*)ybuf;
    short* midbf = (short*)ybuf;
    float* hbuf  = SH;
    short* hnbf  = (short*)(SH + (size_t)TOKENS * DMODEL);

    short* ybf   = (short*)bfarea;
    short* WinT  = ybf + (size_t)TOKENS * DIN;
    short* WoutT = WinT + (size_t)NPAD_IN * DMODEL;
    short* w1T   = WoutT + (size_t)DMODEL * DIN;
    short* w2T   = w1T + (size_t)MLP_INNER * DMODEL;

    dim3 blk(256);

    // 0. conversions / weight transposes
    cvt_kernel<<<dim3(TOKENS * DMODEL / 4 / 256), blk, 0, stream>>>(x, xbf, TOKENS * DMODEL / 4);
    transpose_kernel<<<dim3(NPAD_IN / 32, DMODEL / 32), blk, 0, stream>>>(W_in, WinT, DMODEL, DPROJ);
    transpose_kernel<<<dim3(DMODEL / 32, DIN / 32), blk, 0, stream>>>(W_out, WoutT, DIN, DMODEL);
    transpose_kernel<<<dim3(MLP_INNER / 32, DMODEL / 32), blk, 0, stream>>>(mlp_w1, w1T, DMODEL, MLP_INNER);
    transpose_kernel<<<dim3(DMODEL / 32, MLP_INNER / 32), blk, 0, stream>>>(mlp_w2, w2T, MLP_INNER, DMODEL);

    // 1. zx = x @ W_in  (1088 blocks -> KT=32)
    gemm_bf16_kernel<0, 32><<<dim3(NPAD_IN / 128, TOKENS / 128), blk, 0, stream>>>(
        xbf, WinT, zx, nullptr, nullptr, TOKENS, DPROJ, DMODEL);
    // 2. conv + bias + silu (token-blocked)
    conv_kernel<<<dim3(TOKENS / CTOK, (CONV_DIM / 4 + 255) / 256), blk, 0, stream>>>(
        zx, conv_w, conv_b, xBCc);
    // 3. dt / ldA
    dt_kernel<<<dim3(TOKENS * NH / 256), blk, 0, stream>>>(zx, dt_bias, A_log, dtb, ldab);
    // 4. SSD
    chunk_kernel<<<dim3(NCH), blk, 0, stream>>>(xBCc, dtb, ldab, ybuf, SH, cumdecay);
    state_kernel<<<dim3(BATCH * NH), blk, 0, stream>>>(SH, cumdecay);
    inter_kernel<<<dim3(NCH), blk, 0, stream>>>(xBCc, SH, cumdecay, ybuf);
    // 5. ybf = bf16(rmsnorm((y + D*x) * silu(z)))
    norm1_kernel<<<dim3(TOKENS), blk, 0, stream>>>(zx, xBCc, D_param, ybuf, ybf, norm_w);
    // 6. h = x + ybf @ W_out  (256 blocks -> KT=64)
    gemm_bf16_kernel<3, 64><<<dim3(DMODEL / 128, TOKENS / 128), blk, 0, stream>>>(
        ybf, WoutT, hbuf, nullptr, x, TOKENS, DMODEL, DIN);
    // 7. hnbf = bf16(rmsnorm(h))
    norm2_kernel<<<dim3(TOKENS), blk, 0, stream>>>(hbuf, hnbf, rms_w);
    // 8. midbf = bf16(silu(hnbf @ mlp_w1 + b1))  (1024 blocks -> KT=32)
    gemm_bf16_kernel<1, 32><<<dim3(MLP_INNER / 128, TOKENS / 128), blk, 0, stream>>>(
        hnbf, w1T, midbf, mlp_b1, nullptr, TOKENS, MLP_INNER, DMODEL);
    // 9. out = h + midbf @ mlp_w2 + b2  (256 blocks -> KT=64)
    gemm_bf16_kernel<2, 64><<<dim3(DMODEL / 128, TOKENS / 128), blk, 0, stream>>>(
        midbf, w2T, out, mlp_b2, hbuf, TOKENS, DMODEL, MLP_INNER);
}

// Round 9
// 428.663 us; speedup vs baseline: 1.3703x; 1.0377x over previous
//
#include <hip/hip_runtime.h>
#include <hip/hip_bf16.h>
#include <cstdint>
#include <cstddef>

#define BATCH 2
#define SEQ 2048
#define DMODEL 1024
#define DIN 2048
#define NH 32
#define HEADDIM 64
#define DSTATE 64
#define DCONV 4
#define CONV_DIM (DIN + 2 * DSTATE)          // 2176
#define DPROJ (2 * DIN + 2 * DSTATE + NH)    // 4256
#define MLP_INNER 4096
#define TOKENS (BATCH * SEQ)                 // 4096
#define EPS 1e-5f
#define Q 64
#define NCHUNK (SEQ / Q)                     // 32
#define NCH (BATCH * NCHUNK * NH)            // 2048 chunk-heads
#define LSTR 72                               // 144B rows (16B-aligned)
#define NPAD_IN 4352                          // DPROJ padded to 34*128

typedef __attribute__((ext_vector_type(8))) short short8;
typedef __attribute__((ext_vector_type(8))) __bf16 bf16x8;
typedef __attribute__((ext_vector_type(4))) float f32x4;

__device__ inline short f2bf(float f) {
    unsigned u = __builtin_bit_cast(unsigned, f);
    u = (u + 0x7FFFu + ((u >> 16) & 1u)) >> 16;
    return (short)u;
}
__device__ inline float bf2f(short s) {
    unsigned u = ((unsigned)(unsigned short)s) << 16;
    return __builtin_bit_cast(float, u);
}
__device__ inline float silu_f(float x) { return x / (1.f + __expf(-x)); }

__device__ inline bf16x8 ld_frag(const short* p) {
    short8 s = *(const short8*)p;
    return __builtin_bit_cast(bf16x8, s);
}

__device__ inline void glds16(const short* g, short* l) {
    __builtin_amdgcn_global_load_lds(
        (const __attribute__((address_space(1))) void*)g,
        (__attribute__((address_space(3))) void*)l, 16, 0, 0);
}

// ---------------- bf16 GEMM: m97 staging + dbuf + XCD swizzle + XOR-swizzled LDS ----
// MODE 0: f32 C=AB; 1: bf16 C=silu(AB+bias); 2: f32 C=AB+bias+res; 3: f32 C=AB+res;
// MODE 4: bf16 C=AB.  KT=32 kernels run 4 blocks/CU; KT=64 (64KB LDS) capped at 2.
template <int MODE, int KT>
__global__ __launch_bounds__(256, (KT == 32) ? 4 : 2) void gemm_bf16_kernel(
    const short* __restrict__ A, const short* __restrict__ BT,
    void* __restrict__ Cout, const float* __restrict__ bias,
    const float* __restrict__ res, int M, int N, int K)
{
    const int tid  = threadIdx.x;
    const int wid  = tid >> 6;
    const int lane = tid & 63;
    const int lm   = lane & 15;
    const int lg   = lane >> 4;

    const int nb  = gridDim.x * gridDim.y;
    const int bid = blockIdx.y * gridDim.x + blockIdx.x;
    const int per = nb >> 3;
    const int nid = (bid & 7) * per + (bid >> 3);
    const int m0  = (nid / gridDim.x) * 128;
    const int n0  = (nid % gridDim.x) * 128;

    __shared__ __attribute__((aligned(16))) short Al0[128 * KT];
    __shared__ __attribute__((aligned(16))) short Al1[128 * KT];
    __shared__ __attribute__((aligned(16))) short Bl0[128 * KT];
    __shared__ __attribute__((aligned(16))) short Bl1[128 * KT];

    f32x4 acc[4][4];
#pragma unroll
    for (int i = 0; i < 4; ++i)
#pragma unroll
        for (int j = 0; j < 4; ++j) acc[i][j] = {0.f, 0.f, 0.f, 0.f};

    const int wm = (wid >> 1) * 64;
    const int wn = (wid & 1) * 64;

    constexpr int lpr = KT / 8;      // 16B blocks per row
    constexpr int rpi = 64 / lpr;    // rows per glds16 instr
    constexpr int nin = 32 / rpi;    // glds16 instrs per matrix per wave
    const int srow = lane / lpr;
    const int scb  = (lane % lpr) ^ (srow & (lpr - 1));   // swizzled source block
    const int scol = scb * 8;
    const short* Ag = A  + (size_t)(m0 + wid * 32 + srow) * K + scol;
    const short* Bg = BT + (size_t)(n0 + wid * 32 + srow) * K + scol;
    const int woff = wid * 32 * KT;

    const int niter = K / KT;
    {
#pragma unroll
        for (int j = 0; j < nin; ++j) {
            glds16(Ag + (size_t)j * rpi * K, Al0 + woff + j * 512);
            glds16(Bg + (size_t)j * rpi * K, Bl0 + woff + j * 512);
        }
    }

    for (int i = 0; i < niter; ++i) {
        __syncthreads();
        const short* Ac = (i & 1) ? Al1 : Al0;
        const short* Bc = (i & 1) ? Bl1 : Bl0;
        if (i + 1 < niter) {
            int kt = (i + 1) * KT;
            short* al = ((i & 1) ? Al0 : Al1) + woff;
            short* bl = ((i & 1) ? Bl0 : Bl1) + woff;
#pragma unroll
            for (int j = 0; j < nin; ++j) {
                glds16(Ag + kt + (size_t)j * rpi * K, al + j * 512);
                glds16(Bg + kt + (size_t)j * rpi * K, bl + j * 512);
            }
        }

#pragma unroll
        for (int sub = 0; sub < KT / 32; ++sub) {
            const int cb = sub * 4 + lg;
            bf16x8 af[4], bf[4];
#pragma unroll
            for (int ii = 0; ii < 4; ++ii) {
                int ar = wm + ii * 16 + lm;
                af[ii] = ld_frag(&Ac[ar * KT + ((cb ^ (ar & (lpr - 1))) * 8)]);
            }
#pragma unroll
            for (int j = 0; j < 4; ++j) {
                int br = wn + j * 16 + lm;
                bf[j] = ld_frag(&Bc[br * KT + ((cb ^ (br & (lpr - 1))) * 8)]);
            }
#pragma unroll
            for (int ii = 0; ii < 4; ++ii)
#pragma unroll
                for (int j = 0; j < 4; ++j)
                    acc[ii][j] = __builtin_amdgcn_mfma_f32_16x16x32_bf16(af[ii], bf[j], acc[ii][j], 0, 0, 0);
        }
    }

#pragma unroll
    for (int i = 0; i < 4; ++i) {
#pragma unroll
        for (int j = 0; j < 4; ++j) {
            int col = n0 + wn + j * 16 + lm;
            if (col >= N) continue;
            float bv = (MODE == 1 || MODE == 2) ? bias[col] : 0.f;
#pragma unroll
            for (int r = 0; r < 4; ++r) {
                int row = m0 + wm + i * 16 + lg * 4 + r;
                float v = acc[i][j][r];
                if (MODE == 1) {
                    ((short*)Cout)[(size_t)row * N + col] = f2bf(silu_f(v + bv));
                } else if (MODE == 4) {
                    ((short*)Cout)[(size_t)row * N + col] = f2bf(v);
                } else {
                    if (MODE == 2) v = v + bv + res[(size_t)row * N + col];
                    if (MODE == 3) v = v + res[(size_t)row * N + col];
                    ((float*)Cout)[(size_t)row * N + col] = v;
                }
            }
        }
    }
}

// ---------------- f32 -> bf16 convert ----------------
__global__ __launch_bounds__(256) void cvt_kernel(
    const float* __restrict__ src, short* __restrict__ dst, int n4)
{
    int i = (blockIdx.x * 256 + threadIdx.x);
    if (i >= n4) return;
    f32x4 v = *(const f32x4*)(src + (size_t)i * 4);
    short4 o;
    o.x = f2bf(v.x); o.y = f2bf(v.y); o.z = f2bf(v.z); o.w = f2bf(v.w);
    *(short4*)(dst + (size_t)i * 4) = o;
}

// ---------------- W [K][N] f32 -> WT [Npad][K] bf16 ----------------
__global__ __launch_bounds__(256) void transpose_kernel(
    const float* __restrict__ src, short* __restrict__ dst, int K, int N)
{
    __shared__ float t[32][33];
    int bx = blockIdx.x, by = blockIdx.y;
    int col = threadIdx.x & 31, row8 = threadIdx.x >> 5;
    int gn = bx * 32 + col;
#pragma unroll
    for (int r = 0; r < 4; ++r) {
        int gk = by * 32 + row8 + r * 8;
        t[row8 + r * 8][col] = (gn < N) ? src[(size_t)gk * N + gn] : 0.f;
    }
    __syncthreads();
#pragma unroll
    for (int r = 0; r < 4; ++r) {
        int n = bx * 32 + row8 + r * 8;
        dst[(size_t)n * K + by * 32 + col] = f2bf(t[col][row8 + r * 8]);
    }
}

// ---------------- depthwise causal conv (k=4) + bias + silu, bf16 in/out ----
#define CTOK 8
__global__ __launch_bounds__(256) void conv_kernel(
    const short* __restrict__ zx, const float* __restrict__ cw,
    const float* __restrict__ cb, short* __restrict__ xBCc)
{
    int c4 = blockIdx.y * 256 + threadIdx.x;
    if (c4 >= CONV_DIM / 4) return;
    int c  = c4 * 4;
    int m0 = blockIdx.x * CTOK;
    int l0 = m0 & (SEQ - 1);

    const short* base = zx + (size_t)m0 * DPROJ + DIN + c;
    f32x4 win[CTOK + 3];
#pragma unroll
    for (int j = 0; j < CTOK + 3; ++j) {
        int off = j - 3;
        if (l0 + off >= 0) {
            short4 sv = *(const short4*)(base + (ptrdiff_t)off * DPROJ);
            win[j] = {bf2f(sv.x), bf2f(sv.y), bf2f(sv.z), bf2f(sv.w)};
        } else {
            win[j] = {0.f, 0.f, 0.f, 0.f};
        }
    }
    f32x4 w0 = *(const f32x4*)(cw + (c + 0) * DCONV);
    f32x4 w1 = *(const f32x4*)(cw + (c + 1) * DCONV);
    f32x4 w2 = *(const f32x4*)(cw + (c + 2) * DCONV);
    f32x4 w3 = *(const f32x4*)(cw + (c + 3) * DCONV);
    f32x4 bb = *(const f32x4*)(cb + c);

    short* outp = xBCc + (size_t)m0 * CONV_DIM + c;
#pragma unroll
    for (int t = 0; t < CTOK; ++t) {
        f32x4 a = {bb.x, bb.y, bb.z, bb.w};
#pragma unroll
        for (int j = 0; j < DCONV; ++j) {
            f32x4 v = win[t + j];
            a.x += v.x * w0[j];
            a.y += v.y * w1[j];
            a.z += v.z * w2[j];
            a.w += v.w * w3[j];
        }
        short4 o;
        o.x = f2bf(silu_f(a.x)); o.y = f2bf(silu_f(a.y));
        o.z = f2bf(silu_f(a.z)); o.w = f2bf(silu_f(a.w));
        *(short4*)(outp + (size_t)t * CONV_DIM) = o;
    }
}

// ---------------- dt = softplus(dt_raw + bias); ldA = A * dt ----------------
__global__ __launch_bounds__(256) void dt_kernel(
    const short* __restrict__ zx, const float* __restrict__ dt_bias,
    const float* __restrict__ A_log, float* __restrict__ dtb, float* __restrict__ ldab)
{
    int idx = blockIdx.x * 256 + threadIdx.x;
    if (idx >= TOKENS * NH) return;
    int hh = idx & (NH - 1);
    int m  = idx >> 5;
    float v  = bf2f(zx[(size_t)m * DPROJ + DIN + CONV_DIM + hh]) + dt_bias[hh];
    float dt = (v > 20.f) ? v : log1pf(__expf(v));
    dtb[idx]  = dt;
    ldab[idx] = -__expf(A_log[hh]) * dt;
}

// ---------------- P1: intra-chunk SSD (bf16 xBCc) ----------------
__global__ __launch_bounds__(256) void chunk_kernel(
    const short* __restrict__ xBCc, const float* __restrict__ dtb,
    const float* __restrict__ ldab, float* __restrict__ ybuf,
    float* __restrict__ Sbuf, float* __restrict__ cumdecay)
{
    int bid = blockIdx.x;
    int h = bid & 31, c = (bid >> 5) & 31, b = bid >> 10;
    int m0 = b * SEQ + c * Q;
    int tid = threadIdx.x;
    int wid = tid >> 6, lane = tid & 63, lm = lane & 15, lg = lane >> 4;

    __shared__ __attribute__((aligned(16))) short Cc[64 * LSTR];
    __shared__ __attribute__((aligned(16))) short Bb[64 * LSTR];
    __shared__ __attribute__((aligned(16))) short BwT[64 * LSTR];
    __shared__ __attribute__((aligned(16))) short Xt[64 * LSTR];
    __shared__ __attribute__((aligned(16))) short Mm[64 * LSTR];
    __shared__ float Lc[64], dtv[64];

    if (tid < 64) {
        int s = tid;
        size_t ix = (size_t)(m0 + s) * NH + h;
        float ld = ldab[ix];
        float dt = dtb[ix];
        float v = ld;
#pragma unroll
        for (int off = 1; off < 64; off <<= 1) {
            float o = __shfl_up(v, off);
            if (s >= off) v += o;
        }
        Lc[s] = v;
        dtv[s] = dt;
        cumdecay[(size_t)bid * 64 + s] = __expf(v);
    }
    {
        int row = tid >> 2, c0 = (tid & 3) * 16;
        const short* pB = xBCc + (size_t)(m0 + row) * CONV_DIM + DIN;
#pragma unroll
        for (int u = 0; u < 2; ++u) {
            short8 vb = *(const short8*)(pB + c0 + 8 * u);
            short8 vc = *(const short8*)(pB + DSTATE + c0 + 8 * u);
            *(short8*)&Bb[row * LSTR + c0 + 8 * u] = vb;
            *(short8*)&Cc[row * LSTR + c0 + 8 * u] = vc;
        }
    }
    __syncthreads();
    {
        int s = tid >> 2, c0 = (tid & 3) * 16;
        float w = dtv[s];
        float w2 = __expf(Lc[63] - Lc[s]);
        const short* pX = xBCc + (size_t)(m0 + s) * CONV_DIM + h * HEADDIM;
#pragma unroll
        for (int u = 0; u < 4; ++u) {
            short4 v = *(const short4*)(pX + c0 + 4 * u);
            Xt[(c0 + 4 * u + 0) * LSTR + s] = f2bf(bf2f(v.x) * w);
            Xt[(c0 + 4 * u + 1) * LSTR + s] = f2bf(bf2f(v.y) * w);
            Xt[(c0 + 4 * u + 2) * LSTR + s] = f2bf(bf2f(v.z) * w);
            Xt[(c0 + 4 * u + 3) * LSTR + s] = f2bf(bf2f(v.w) * w);
            short4 sb = *(short4*)&Bb[s * LSTR + c0 + 4 * u];
            BwT[(c0 + 4 * u + 0) * LSTR + s] = f2bf(bf2f(sb.x) * w2);
            BwT[(c0 + 4 * u + 1) * LSTR + s] = f2bf(bf2f(sb.y) * w2);
            BwT[(c0 + 4 * u + 2) * LSTR + s] = f2bf(bf2f(sb.z) * w2);
            BwT[(c0 + 4 * u + 3) * LSTR + s] = f2bf(bf2f(sb.w) * w2);
        }
    }
    __syncthreads();

    {
        bf16x8 af[2];
#pragma unroll
        for (int kk = 0; kk < 2; ++kk)
            af[kk] = ld_frag(&Cc[(wid * 16 + lm) * LSTR + kk * 32 + lg * 8]);
#pragma unroll
        for (int j = 0; j < 4; ++j) {
            f32x4 acc = {0.f, 0.f, 0.f, 0.f};
#pragma unroll
            for (int kk = 0; kk < 2; ++kk) {
                bf16x8 bf = ld_frag(&Bb[(j * 16 + lm) * LSTR + kk * 32 + lg * 8]);
                acc = __builtin_amdgcn_mfma_f32_16x16x32_bf16(af[kk], bf, acc, 0, 0, 0);
            }
            int s = j * 16 + lm;
            float Ls = Lc[s];
#pragma unroll
            for (int r = 0; r < 4; ++r) {
                int t = wid * 16 + lg * 4 + r;
                float val = (s <= t) ? acc[r] * __expf(Lc[t] - Ls) : 0.f;
                Mm[t * LSTR + s] = f2bf(val);
            }
        }
    }
    __syncthreads();

    {
        bf16x8 am[2], aw[2];
#pragma unroll
        for (int kk = 0; kk < 2; ++kk) {
            am[kk] = ld_frag(&Mm[(wid * 16 + lm) * LSTR + kk * 32 + lg * 8]);
            aw[kk] = ld_frag(&BwT[(wid * 16 + lm) * LSTR + kk * 32 + lg * 8]);
        }
#pragma unroll
        for (int j = 0; j < 4; ++j) {
            f32x4 a1 = {0.f, 0.f, 0.f, 0.f};
            f32x4 a2 = {0.f, 0.f, 0.f, 0.f};
#pragma unroll
            for (int kk = 0; kk < 2; ++kk) {
                bf16x8 bx = ld_frag(&Xt[(j * 16 + lm) * LSTR + kk * 32 + lg * 8]);
                a1 = __builtin_amdgcn_mfma_f32_16x16x32_bf16(am[kk], bx, a1, 0, 0, 0);
                a2 = __builtin_amdgcn_mfma_f32_16x16x32_bf16(aw[kk], bx, a2, 0, 0, 0);
            }
            int p = j * 16 + lm;
#pragma unroll
            for (int r = 0; r < 4; ++r) {
                int t = wid * 16 + lg * 4 + r;
                ybuf[(size_t)(m0 + t) * DIN + h * HEADDIM + p] = a1[r];
                Sbuf[(size_t)bid * 4096 + t * 64 + p] = a2[r];
            }
        }
    }
}

// ---------------- P2: inter-chunk state recurrence ----------------
__global__ __launch_bounds__(256) void state_kernel(
    float* __restrict__ SH, const float* __restrict__ cumdecay)
{
    int bh = blockIdx.x;
    int b = bh >> 5, h = bh & 31;
    int tid = threadIdx.x;
    f32x4 H[4];
#pragma unroll
    for (int u = 0; u < 4; ++u) H[u] = {0.f, 0.f, 0.f, 0.f};
    for (int c = 0; c < NCHUNK; ++c) {
        int cid = (b * NCHUNK + c) * NH + h;
        size_t base = (size_t)cid * 4096 + (size_t)tid * 16;
        float cd = cumdecay[(size_t)cid * 64 + 63];
        f32x4 s[4];
#pragma unroll
        for (int u = 0; u < 4; ++u) s[u] = *(const f32x4*)(SH + base + u * 4);
#pragma unroll
        for (int u = 0; u < 4; ++u) *(f32x4*)(SH + base + u * 4) = H[u];
#pragma unroll
        for (int u = 0; u < 4; ++u) {
            H[u].x = cd * H[u].x + s[u].x;
            H[u].y = cd * H[u].y + s[u].y;
            H[u].z = cd * H[u].z + s[u].z;
            H[u].w = cd * H[u].w + s[u].w;
        }
    }
}

// ---------------- P3: y += exp(Lc_t) * C_t @ H_in ----------------
__global__ __launch_bounds__(256) void inter_kernel(
    const short* __restrict__ xBCc, const float* __restrict__ Hin,
    const float* __restrict__ cumdecay, float* __restrict__ ybuf)
{
    int bid = blockIdx.x;
    int h = bid & 31, c = (bid >> 5) & 31, b = bid >> 10;
    int m0 = b * SEQ + c * Q;
    int tid = threadIdx.x;
    int wid = tid >> 6, lane = tid & 63, lm = lane & 15, lg = lane >> 4;

    __shared__ __attribute__((aligned(16))) short Cc[64 * LSTR];
    __shared__ __attribute__((aligned(16))) short HT[64 * LSTR];
    __shared__ float eLc[64];

    if (tid < 64) eLc[tid] = cumdecay[(size_t)bid * 64 + tid];
    {
        int row = tid >> 2, c0 = (tid & 3) * 16;
        const short* pC = xBCc + (size_t)(m0 + row) * CONV_DIM + DIN + DSTATE;
#pragma unroll
        for (int u = 0; u < 2; ++u) {
            short8 vc = *(const short8*)(pC + c0 + 8 * u);
            *(short8*)&Cc[row * LSTR + c0 + 8 * u] = vc;
        }
        const float* pH = Hin + (size_t)bid * 4096 + row * 64;
#pragma unroll
        for (int u = 0; u < 4; ++u) {
            f32x4 vh = *(const f32x4*)(pH + c0 + 4 * u);
            HT[(c0 + 4 * u + 0) * LSTR + row] = f2bf(vh.x);
            HT[(c0 + 4 * u + 1) * LSTR + row] = f2bf(vh.y);
            HT[(c0 + 4 * u + 2) * LSTR + row] = f2bf(vh.z);
            HT[(c0 + 4 * u + 3) * LSTR + row] = f2bf(vh.w);
        }
    }
    __syncthreads();

    bf16x8 af[2];
#pragma unroll
    for (int kk = 0; kk < 2; ++kk)
        af[kk] = ld_frag(&Cc[(wid * 16 + lm) * LSTR + kk * 32 + lg * 8]);
#pragma unroll
    for (int j = 0; j < 4; ++j) {
        f32x4 acc = {0.f, 0.f, 0.f, 0.f};
#pragma unroll
        for (int kk = 0; kk < 2; ++kk) {
            bf16x8 bh_ = ld_frag(&HT[(j * 16 + lm) * LSTR + kk * 32 + lg * 8]);
            acc = __builtin_amdgcn_mfma_f32_16x16x32_bf16(af[kk], bh_, acc, 0, 0, 0);
        }
        int p = j * 16 + lm;
#pragma unroll
        for (int r = 0; r < 4; ++r) {
            int t = wid * 16 + lg * 4 + r;
            size_t ya = (size_t)(m0 + t) * DIN + h * HEADDIM + p;
            ybuf[ya] += eLc[t] * acc[r];
        }
    }
}

// ---------------- ybf = bf16(rmsnorm((y + D*x) * silu(z), norm_w)) ----------------
__global__ __launch_bounds__(256) void norm1_kernel(
    const short* __restrict__ zx, const short* __restrict__ xBCc,
    const float* __restrict__ Dp, const float* __restrict__ y,
    short* __restrict__ ybf, const float* __restrict__ w)
{
    int m = blockIdx.x;
    int t = threadIdx.x;
    const short* zr = zx + (size_t)m * DPROJ;
    const short* xr = xBCc + (size_t)m * CONV_DIM;
    const float* yr = y + (size_t)m * DIN;
    float vals[8];
    float ss = 0.f;
#pragma unroll
    for (int j = 0; j < 8; ++j) {
        int i = j * 256 + t;
        float v = (yr[i] + Dp[i >> 6] * bf2f(xr[i])) * silu_f(bf2f(zr[i]));
        vals[j] = v;
        ss += v * v;
    }
#pragma unroll
    for (int o = 32; o >= 1; o >>= 1) ss += __shfl_xor(ss, o);
    __shared__ float wsum[4];
    if ((t & 63) == 0) wsum[t >> 6] = ss;
    __syncthreads();
    float tot = wsum[0] + wsum[1] + wsum[2] + wsum[3];
    float scale = rsqrtf(tot / (float)DIN + EPS);
#pragma unroll
    for (int j = 0; j < 8; ++j) {
        int i = j * 256 + t;
        ybf[(size_t)m * DIN + i] = f2bf(vals[j] * scale * w[i]);
    }
}

// ---------------- hnbf = bf16(rmsnorm(h, rms_w)) ----------------
__global__ __launch_bounds__(256) void norm2_kernel(
    const float* __restrict__ hb, short* __restrict__ hnbf, const float* __restrict__ w)
{
    int m = blockIdx.x;
    int t = threadIdx.x;
    const float* hr = hb + (size_t)m * DMODEL;
    float vals[4];
    float ss = 0.f;
#pragma unroll
    for (int j = 0; j < 4; ++j) {
        int i = j * 256 + t;
        float v = hr[i];
        vals[j] = v;
        ss += v * v;
    }
#pragma unroll
    for (int o = 32; o >= 1; o >>= 1) ss += __shfl_xor(ss, o);
    __shared__ float wsum[4];
    if ((t & 63) == 0) wsum[t >> 6] = ss;
    __syncthreads();
    float tot = wsum[0] + wsum[1] + wsum[2] + wsum[3];
    float scale = rsqrtf(tot / (float)DMODEL + EPS);
#pragma unroll
    for (int j = 0; j < 4; ++j) {
        int i = j * 256 + t;
        hnbf[(size_t)m * DMODEL + i] = f2bf(vals[j] * scale * w[i]);
    }
}

extern "C" void kernel_launch(void* const* d_in, const int* in_sizes, int n_in,
                              void* d_out, int out_size, void* d_ws, size_t ws_size,
                              hipStream_t stream) {
    const float* x       = (const float*)d_in[0];
    const float* W_in    = (const float*)d_in[1];
    const float* conv_w  = (const float*)d_in[2];
    const float* conv_b  = (const float*)d_in[3];
    const float* dt_bias = (const float*)d_in[4];
    const float* A_log   = (const float*)d_in[5];
    const float* D_param = (const float*)d_in[6];
    const float* norm_w  = (const float*)d_in[7];
    const float* W_out   = (const float*)d_in[8];
    const float* rms_w   = (const float*)d_in[9];
    const float* mlp_w1  = (const float*)d_in[10];
    const float* mlp_b1  = (const float*)d_in[11];
    const float* mlp_w2  = (const float*)d_in[12];
    const float* mlp_b2  = (const float*)d_in[13];
    float* out = (float*)d_out;

    // Workspace layout (region sizes kept from R8; zx/xBCc now bf16 within
    // their old f32-sized slots — wasteful but safe).
    float* ws       = (float*)d_ws;
    float* zxf      = ws;                                  // holds bf16 zx
    float* xBCf     = zxf + (size_t)TOKENS * DPROJ;        // holds bf16 xBCc
    float* dtb      = xBCf + (size_t)TOKENS * CONV_DIM;
    float* ldab     = dtb + (size_t)TOKENS * NH;
    float* cumdecay = ldab + (size_t)TOKENS * NH;
    float* ybuf     = cumdecay + (size_t)TOKENS * NH;
    float* SH       = ybuf + (size_t)TOKENS * DIN;
    float* bfarea   = SH + (size_t)NCH * 4096;

    short* zxb   = (short*)zxf;
    short* xBCb  = (short*)xBCf;
    short* xbf   = (short*)ybuf;
    short* midbf = (short*)ybuf;
    float* hbuf  = SH;
    short* hnbf  = (short*)(SH + (size_t)TOKENS * DMODEL);

    short* ybf   = (short*)bfarea;
    short* WinT  = ybf + (size_t)TOKENS * DIN;
    short* WoutT = WinT + (size_t)NPAD_IN * DMODEL;
    short* w1T   = WoutT + (size_t)DMODEL * DIN;
    short* w2T   = w1T + (size_t)MLP_INNER * DMODEL;

    dim3 blk(256);

    // 0. conversions / weight transposes
    cvt_kernel<<<dim3(TOKENS * DMODEL / 4 / 256), blk, 0, stream>>>(x, xbf, TOKENS * DMODEL / 4);
    transpose_kernel<<<dim3(NPAD_IN / 32, DMODEL / 32), blk, 0, stream>>>(W_in, WinT, DMODEL, DPROJ);
    transpose_kernel<<<dim3(DMODEL / 32, DIN / 32), blk, 0, stream>>>(W_out, WoutT, DIN, DMODEL);
    transpose_kernel<<<dim3(MLP_INNER / 32, DMODEL / 32), blk, 0, stream>>>(mlp_w1, w1T, DMODEL, MLP_INNER);
    transpose_kernel<<<dim3(DMODEL / 32, MLP_INNER / 32), blk, 0, stream>>>(mlp_w2, w2T, MLP_INNER, DMODEL);

    // 1. zx = bf16(x @ W_in)  (1088 blocks -> KT=32, 4 blk/CU)
    gemm_bf16_kernel<4, 32><<<dim3(NPAD_IN / 128, TOKENS / 128), blk, 0, stream>>>(
        xbf, WinT, zxb, nullptr, nullptr, TOKENS, DPROJ, DMODEL);
    // 2. conv + bias + silu (bf16 in/out, token-blocked)
    conv_kernel<<<dim3(TOKENS / CTOK, (CONV_DIM / 4 + 255) / 256), blk, 0, stream>>>(
        zxb, conv_w, conv_b, xBCb);
    // 3. dt / ldA
    dt_kernel<<<dim3(TOKENS * NH / 256), blk, 0, stream>>>(zxb, dt_bias, A_log, dtb, ldab);
    // 4. SSD
    chunk_kernel<<<dim3(NCH), blk, 0, stream>>>(xBCb, dtb, ldab, ybuf, SH, cumdecay);
    state_kernel<<<dim3(BATCH * NH), blk, 0, stream>>>(SH, cumdecay);
    inter_kernel<<<dim3(NCH), blk, 0, stream>>>(xBCb, SH, cumdecay, ybuf);
    // 5. ybf = bf16(rmsnorm((y + D*x) * silu(z)))
    norm1_kernel<<<dim3(TOKENS), blk, 0, stream>>>(zxb, xBCb, D_param, ybuf, ybf, norm_w);
    // 6. h = x + ybf @ W_out  (256 blocks -> KT=64)
    gemm_bf16_kernel<3, 64><<<dim3(DMODEL / 128, TOKENS / 128), blk, 0, stream>>>(
        ybf, WoutT, hbuf, nullptr, x, TOKENS, DMODEL, DIN);
    // 7. hnbf = bf16(rmsnorm(h))
    norm2_kernel<<<dim3(TOKENS), blk, 0, stream>>>(hbuf, hnbf, rms_w);
    // 8. midbf = bf16(silu(hnbf @ mlp_w1 + b1))  (1024 blocks -> KT=32, 4 blk/CU)
    gemm_bf16_kernel<1, 32><<<dim3(MLP_INNER / 128, TOKENS / 128), blk, 0, stream>>>(
        hnbf, w1T, midbf, mlp_b1, nullptr, TOKENS, MLP_INNER, DMODEL);
    // 9. out = h + midbf @ mlp_w2 + b2  (256 blocks -> KT=64)
    gemm_bf16_kernel<2, 64><<<dim3(DMODEL / 128, TOKENS / 128), blk, 0, stream>>>(
        midbf, w2T, out, mlp_b2, hbuf, TOKENS, DMODEL, MLP_INNER);
}